// Round 4
// baseline (19617.931 us; speedup 1.0000x reference)
//
#include <hip/hip_runtime.h>
#include <hip/hip_bf16.h>

#define D 300
#define D2 150          // bf16 pairs per row
#define HD 600
#define NLAYERS 5
#define BN_EPS 1e-5f

// ---------------------------------------------------------------- bf16 helpers
__device__ inline ushort f2bf(float x) {
    __hip_bfloat16 b = __float2bfloat16(x);
    return *reinterpret_cast<ushort*>(&b);
}
__device__ inline float bf2f(ushort u) {
    __hip_bfloat16 b;
    *reinterpret_cast<ushort*>(&b) = u;
    return __bfloat162float(b);
}
__device__ inline uint pack2(float lo, float hi) {
    return (uint)f2bf(lo) | ((uint)f2bf(hi) << 16);
}

// CAS-based packed bf16x2 atomic add (compiles everywhere; low contention here:
// avg degree E/N = 2, so retry rate ~0)
__device__ inline void atomic_add_bf16x2(uint* addr, float addlo, float addhi) {
    uint old = *addr;
    uint assumed;
    do {
        assumed = old;
        float lo = bf2f((ushort)(assumed & 0xffffu)) + addlo;
        float hi = bf2f((ushort)(assumed >> 16))     + addhi;
        old = atomicCAS(addr, assumed, pack2(lo, hi));
    } while (old != assumed);
}

// ---------------------------------------------------------------- zero fill (uint4)
__global__ __launch_bounds__(256) void zero_kernel(uint4* __restrict__ p, long n4)
{
    long i = (long)blockIdx.x * blockDim.x + threadIdx.x;
    long stride = (long)gridDim.x * blockDim.x;
    uint4 z = make_uint4(0u, 0u, 0u, 0u);
    for (; i < n4; i += stride) p[i] = z;
}

// ---------------------------------------------------------------- embed  (h bf16)
// h[i,:] = node_emb0[an[i],:] + node_emb1[ch[i],:]   (wave per node)
__global__ __launch_bounds__(256) void embed_kernel(
    const int* __restrict__ an, const int* __restrict__ ch,
    const float* __restrict__ e0, const float* __restrict__ e1,
    uint* __restrict__ h_u, int N)
{
    int node = blockIdx.x * 4 + (threadIdx.x >> 6);
    if (node >= N) return;
    int lane = threadIdx.x & 63;
    const float* r0 = e0 + (size_t)an[node] * D;
    const float* r1 = e1 + (size_t)ch[node] * D;
    uint* hr = h_u + (size_t)node * D2;
    for (int d2 = lane; d2 < D2; d2 += 64) {
        float2 a = *(const float2*)(r0 + d2 * 2);
        float2 b = *(const float2*)(r1 + d2 * 2);
        hr[d2] = pack2(a.x + b.x, a.y + b.y);
    }
}

// ---------------------------------------------------------------- message + scatter (bf16 agg, CAS atomics)
// agg[dst[e],:] += h[src[e],:] + ee0[bt[e],:] + ee1[bd[e],:]   (wave per edge)
__global__ __launch_bounds__(256) void message_kernel(
    const uint* __restrict__ h_u,
    const float* __restrict__ ee0, const float* __restrict__ ee1,
    const int* __restrict__ bt, const int* __restrict__ bd,
    const int* __restrict__ src, const int* __restrict__ dst,
    uint* __restrict__ agg_u, int E)
{
    int e = blockIdx.x * 4 + (threadIdx.x >> 6);
    if (e >= E) return;
    int lane = threadIdx.x & 63;
    const uint*  hs = h_u + (size_t)src[e] * D2;
    const float* t0 = ee0 + (size_t)bt[e] * D;
    const float* t1 = ee1 + (size_t)bd[e] * D;
    uint* ag = agg_u + (size_t)dst[e] * D2;
    for (int d2 = lane; d2 < D2; d2 += 64) {
        uint hv = hs[d2];
        float2 a = *(const float2*)(t0 + d2 * 2);
        float2 b = *(const float2*)(t1 + d2 * 2);
        float lo = bf2f((ushort)(hv & 0xffffu)) + a.x + b.x;
        float hi = bf2f((ushort)(hv >> 16))     + a.y + b.y;
        atomic_add_bf16x2(ag + d2, lo, hi);
    }
}

// ---------------------------------------------------------------- BN fold prep
// scale = gamma*rsqrt(var+eps); shift = (b2-mean)*scale + beta   (all [L*D] flat)
__global__ void prep_bn_kernel(
    const float* __restrict__ b2, const float* __restrict__ gamma,
    const float* __restrict__ beta, const float* __restrict__ mean,
    const float* __restrict__ var, float* __restrict__ scale2,
    float* __restrict__ shift2, int n)
{
    int i = blockIdx.x * blockDim.x + threadIdx.x;
    if (i >= n) return;
    float s = gamma[i] * rsqrtf(var[i] + BN_EPS);
    scale2[i] = s;
    shift2[i] = (b2[i] - mean[i]) * s + beta[i];
}

// ---------------------------------------------------------------- GEMM + epilogue
// A bf16 [M,K], B f32 [K,Nc], C bf16 [M,Nc] = epi(A@B); epi: y = dot*scale[c]+shift[c]; opt relu
// f32 accumulate. BM=128 BN=64 BK=20 (20|300, 20|600), 256 thr, 8x4 microtile.
template<bool HAS_SCALE, bool RELU>
__global__ __launch_bounds__(256) void gemm_epi_kernel(
    const ushort* __restrict__ A, const float* __restrict__ B,
    const float* __restrict__ scale, const float* __restrict__ shift,
    ushort* __restrict__ C, int M, int K, int Nc)
{
    const int BM = 128, BNc = 64, BK = 20;
    __shared__ float As[BK][BM + 4];   // transposed, padded
    __shared__ float Bs[BK][BNc + 4];
    int t = threadIdx.x;
    int tx = t & 15, ty = t >> 4;       // 16x16 thread grid
    int m0 = blockIdx.x * BM;
    int n0 = blockIdx.y * BNc;
    const uint* Au = (const uint*)A;    // 2 bf16 per uint; K even so rows stay uint-aligned
    int K2 = K >> 1;

    float acc[8][4];
#pragma unroll
    for (int i = 0; i < 8; i++)
#pragma unroll
        for (int j = 0; j < 4; j++) acc[i][j] = 0.f;

    int nk = K / BK;
    for (int kt = 0; kt < nk; ++kt) {
        int k0 = kt * BK;
        // A tile: 128 x 20 bf16 = 1280 uints, store transposed + converted
#pragma unroll
        for (int i = 0; i < 5; ++i) {
            int idx = t + i * 256;            // [0,1280)
            int m = idx / 10, kp = idx - m * 10;
            int gm = m0 + m;
            uint v = 0u;
            if (gm < M) v = Au[(size_t)gm * K2 + (k0 >> 1) + kp];
            As[kp * 2][m]     = bf2f((ushort)(v & 0xffffu));
            As[kp * 2 + 1][m] = bf2f((ushort)(v >> 16));
        }
        // B tile: 20 x 64 = 1280 f32
#pragma unroll
        for (int i = 0; i < 5; ++i) {
            int idx = t + i * 256;
            int n = idx & 63, k = idx >> 6;
            int gn = n0 + n;
            float v = 0.f;
            if (gn < Nc) v = B[(size_t)(k0 + k) * Nc + gn];
            Bs[k][n] = v;
        }
        __syncthreads();
#pragma unroll
        for (int k = 0; k < BK; ++k) {
            float4 a0 = *(const float4*)&As[k][ty * 8];
            float4 a1 = *(const float4*)&As[k][ty * 8 + 4];
            float4 b  = *(const float4*)&Bs[k][tx * 4];
            float av[8] = {a0.x, a0.y, a0.z, a0.w, a1.x, a1.y, a1.z, a1.w};
            float bv[4] = {b.x, b.y, b.z, b.w};
#pragma unroll
            for (int i = 0; i < 8; i++)
#pragma unroll
                for (int j = 0; j < 4; j++)
                    acc[i][j] = fmaf(av[i], bv[j], acc[i][j]);
        }
        __syncthreads();
    }

    // epilogue -> bf16
    int cbase = n0 + tx * 4;
    float sc[4], sh[4];
#pragma unroll
    for (int j = 0; j < 4; j++) {
        int c = cbase + j;
        sc[j] = 1.f; sh[j] = 0.f;
        if (c < Nc) { if (HAS_SCALE) sc[j] = scale[c]; sh[j] = shift[c]; }
    }
#pragma unroll
    for (int i = 0; i < 8; i++) {
        int r = m0 + ty * 8 + i;
        if (r < M && cbase < Nc) {
            ushort4 o;
            float y0 = acc[i][0] * sc[0] + sh[0];
            float y1 = acc[i][1] * sc[1] + sh[1];
            float y2 = acc[i][2] * sc[2] + sh[2];
            float y3 = acc[i][3] * sc[3] + sh[3];
            if (RELU) {
                y0 = fmaxf(y0, 0.f); y1 = fmaxf(y1, 0.f);
                y2 = fmaxf(y2, 0.f); y3 = fmaxf(y3, 0.f);
            }
            o.x = f2bf(y0); o.y = f2bf(y1); o.z = f2bf(y2); o.w = f2bf(y3);
            *(ushort4*)&C[(size_t)r * Nc + cbase] = o;   // 8B aligned: Nc%4==0, row strides 600/1200B
        }
    }
}

// ---------------------------------------------------------------- avg pool (sorted graph_ids, binary search, no atomics)
__global__ __launch_bounds__(320) void pool_kernel(
    const ushort* __restrict__ h, const int* __restrict__ gid,
    float* __restrict__ gavg, int N)
{
    int g = blockIdx.x;
    int lo = 0, hi = N;
    while (lo < hi) { int mid = (lo + hi) >> 1; if (gid[mid] < g) lo = mid + 1; else hi = mid; }
    int start = lo;
    lo = start; hi = N;
    while (lo < hi) { int mid = (lo + hi) >> 1; if (gid[mid] <= g) lo = mid + 1; else hi = mid; }
    int end = lo;
    int d = threadIdx.x;
    if (d >= D) return;
    float s = 0.f;
    for (int i = start; i < end; ++i) s += bf2f(h[(size_t)i * D + d]);
    float cnt = (float)(end - start);
    gavg[(size_t)g * D + d] = s / fmaxf(cnt, 1.f);
}

// ---------------------------------------------------------------- head: out[g,:] = gavg[g,:] @ Wd + bd
__global__ __launch_bounds__(256) void head_kernel(
    const float* __restrict__ gavg, const float* __restrict__ Wd,
    const float* __restrict__ bd, float* __restrict__ out)
{
    int g = blockIdx.x;
    int j = threadIdx.x;           // 256 outputs
    float s = bd[j];
    const float* gr = gavg + (size_t)g * D;
    for (int d = 0; d < D; ++d) s = fmaf(gr[d], Wd[(size_t)d * 256 + j], s);
    out[(size_t)g * 256 + j] = s;
}

// ================================================================ launch
extern "C" void kernel_launch(void* const* d_in, const int* in_sizes, int n_in,
                              void* d_out, int out_size, void* d_ws, size_t ws_size,
                              hipStream_t stream)
{
    const int*   atomic_number = (const int*)d_in[0];
    const int*   chirality     = (const int*)d_in[1];
    const int*   bond_type     = (const int*)d_in[2];
    const int*   bond_dir      = (const int*)d_in[3];
    const int*   src           = (const int*)d_in[4];
    const int*   dst           = (const int*)d_in[5];
    const int*   graph_ids     = (const int*)d_in[6];
    // d_in[7] = num_graphs (device scalar; G derived from out_size instead)
    const float* node_emb0     = (const float*)d_in[8];
    const float* node_emb1     = (const float*)d_in[9];
    const float* edge_emb0     = (const float*)d_in[10];
    const float* edge_emb1     = (const float*)d_in[11];
    const float* W1            = (const float*)d_in[12];
    const float* b1            = (const float*)d_in[13];
    const float* W2            = (const float*)d_in[14];
    const float* b2            = (const float*)d_in[15];
    const float* bn_gamma      = (const float*)d_in[16];
    const float* bn_beta       = (const float*)d_in[17];
    const float* bn_mean       = (const float*)d_in[18];
    const float* bn_var        = (const float*)d_in[19];
    const float* Wd            = (const float*)d_in[20];
    const float* bd            = (const float*)d_in[21];

    int N = in_sizes[0];
    int E = in_sizes[2];
    int G = out_size / 256;
    float* out = (float*)d_out;

    // ---- ws layout: bf16 state buffers (h, agg), small f32 buffers, chunked bf16 hidden ----
    char* ws = (char*)d_ws;
    size_t offs = 0;
    auto take = [&](size_t nbytes) -> char* {
        char* p = ws + offs;
        offs += (nbytes + 255) & ~(size_t)255;
        return p;
    };
    ushort* h      = (ushort*)take((size_t)N * D * 2);        // bf16 [N,D]
    ushort* agg    = (ushort*)take((size_t)N * D * 2);        // bf16 [N,D]
    float*  gavg   = (float*)take((size_t)G * D * 4);
    float*  scale2 = (float*)take((size_t)NLAYERS * D * 4);
    float*  shift2 = (float*)take((size_t)NLAYERS * D * 4);

    size_t avail = ws_size > offs ? ws_size - offs : 0;
    long max_rows = (long)(avail / ((size_t)HD * 2));
    int chunk;
    if (max_rows >= N) chunk = N;
    else {
        chunk = (int)((max_rows / 128) * 128);
        if (chunk < 128) chunk = 128;
    }
    ushort* hidden = (ushort*)take((size_t)chunk * HD * 2);   // bf16 [chunk,HD]

    // BN fold (tiny)
    prep_bn_kernel<<<(NLAYERS * D + 255) / 256, 256, 0, stream>>>(
        b2, bn_gamma, bn_beta, bn_mean, bn_var, scale2, shift2, NLAYERS * D);

    // input embedding
    embed_kernel<<<(N + 3) / 4, 256, 0, stream>>>(
        atomic_number, chirality, node_emb0, node_emb1, (uint*)h, N);

    long agg_u4 = (long)N * D2 / 4;     // N*150 uints / 4 per uint4
    int zgrid = (int)((agg_u4 + 255) / 256);
    if (zgrid > 4096) zgrid = 4096;

    for (int l = 0; l < NLAYERS; ++l) {
        zero_kernel<<<zgrid, 256, 0, stream>>>((uint4*)agg, agg_u4);
        message_kernel<<<(E + 3) / 4, 256, 0, stream>>>(
            (const uint*)h,
            edge_emb0 + (size_t)l * 6 * D,
            edge_emb1 + (size_t)l * 3 * D,
            bond_type, bond_dir, src, dst, (uint*)agg, E);

        for (int r0 = 0; r0 < N; r0 += chunk) {
            int cr = N - r0 < chunk ? N - r0 : chunk;
            dim3 g1((cr + 127) / 128, (HD + 63) / 64);
            dim3 g2((cr + 127) / 128, (D + 63) / 64);
            // hidden = relu(agg_chunk @ W1[l] + b1[l])
            gemm_epi_kernel<false, true><<<g1, 256, 0, stream>>>(
                agg + (size_t)r0 * D, W1 + (size_t)l * D * HD,
                nullptr, b1 + (size_t)l * HD,
                hidden, cr, D, HD);
            // h_chunk = BN(hidden @ W2[l] + b2[l]) (+relu unless last layer)
            if (l < NLAYERS - 1)
                gemm_epi_kernel<true, true><<<g2, 256, 0, stream>>>(
                    hidden, W2 + (size_t)l * HD * D, scale2 + (size_t)l * D,
                    shift2 + (size_t)l * D, h + (size_t)r0 * D, cr, HD, D);
            else
                gemm_epi_kernel<true, false><<<g2, 256, 0, stream>>>(
                    hidden, W2 + (size_t)l * HD * D, scale2 + (size_t)l * D,
                    shift2 + (size_t)l * D, h + (size_t)r0 * D, cr, HD, D);
        }
    }

    pool_kernel<<<G, 320, 0, stream>>>(h, graph_ids, gavg, N);
    head_kernel<<<G, 256, 0, stream>>>(gavg, Wd, bd, out);
}

// Round 5
// 6063.676 us; speedup vs baseline: 3.2353x; 3.2353x over previous
//
#include <hip/hip_runtime.h>
#include <hip/hip_bf16.h>

#define D 300
#define D2 150          // bf16 pairs per row
#define HD 600
#define NLAYERS 5
#define BN_EPS 1e-5f

// GEMM1: K=300->Kp=320 (KS1=10 ksteps), N=600->Np=640 (NT1=5 col tiles)
// GEMM2: K=600->Kp=640 (KS2=20),        N=300->Np=384 (NT2=3)
#define KS1 10
#define NT1 5
#define KS2 20
#define NT2 3
#define P1 (NT1*KS1*4096)   // 204800 elems per layer (w1 tiled)
#define P2 (NT2*KS2*4096)   // 245760 elems per layer (w2 tiled)

typedef __attribute__((ext_vector_type(8))) short short8v;
typedef __attribute__((ext_vector_type(4))) float f32x4;

// ---------------------------------------------------------------- bf16 helpers
__device__ inline ushort f2bf(float x) {
    __hip_bfloat16 b = __float2bfloat16(x);
    return *reinterpret_cast<ushort*>(&b);
}
__device__ inline float bf2f(ushort u) {
    __hip_bfloat16 b;
    *reinterpret_cast<ushort*>(&b) = u;
    return __bfloat162float(b);
}
__device__ inline uint pack2(float lo, float hi) {
    return (uint)f2bf(lo) | ((uint)f2bf(hi) << 16);
}

// CAS-based packed bf16x2 atomic add (avg degree E/N = 2 -> ~no retries)
__device__ inline void atomic_add_bf16x2(uint* addr, float addlo, float addhi) {
    uint old = *addr;
    uint assumed;
    do {
        assumed = old;
        float lo = bf2f((ushort)(assumed & 0xffffu)) + addlo;
        float hi = bf2f((ushort)(assumed >> 16))     + addhi;
        old = atomicCAS(addr, assumed, pack2(lo, hi));
    } while (old != assumed);
}

// ---------------------------------------------------------------- zero fill
__global__ __launch_bounds__(256) void zero_kernel(uint4* __restrict__ p, long n4)
{
    long i = (long)blockIdx.x * blockDim.x + threadIdx.x;
    long stride = (long)gridDim.x * blockDim.x;
    uint4 z = make_uint4(0u, 0u, 0u, 0u);
    for (; i < n4; i += stride) p[i] = z;
}

// ---------------------------------------------------------------- embed (h bf16)
__global__ __launch_bounds__(256) void embed_kernel(
    const int* __restrict__ an, const int* __restrict__ ch,
    const float* __restrict__ e0, const float* __restrict__ e1,
    uint* __restrict__ h_u, int N)
{
    int node = blockIdx.x * 4 + (threadIdx.x >> 6);
    if (node >= N) return;
    int lane = threadIdx.x & 63;
    const float* r0 = e0 + (size_t)an[node] * D;
    const float* r1 = e1 + (size_t)ch[node] * D;
    uint* hr = h_u + (size_t)node * D2;
    for (int d2 = lane; d2 < D2; d2 += 64) {
        float2 a = *(const float2*)(r0 + d2 * 2);
        float2 b = *(const float2*)(r1 + d2 * 2);
        hr[d2] = pack2(a.x + b.x, a.y + b.y);
    }
}

// ---------------------------------------------------------------- message + scatter
__global__ __launch_bounds__(256) void message_kernel(
    const uint* __restrict__ h_u,
    const float* __restrict__ ee0, const float* __restrict__ ee1,
    const int* __restrict__ bt, const int* __restrict__ bd,
    const int* __restrict__ src, const int* __restrict__ dst,
    uint* __restrict__ agg_u, int E)
{
    int e = blockIdx.x * 4 + (threadIdx.x >> 6);
    if (e >= E) return;
    int lane = threadIdx.x & 63;
    const uint*  hs = h_u + (size_t)src[e] * D2;
    const float* t0 = ee0 + (size_t)bt[e] * D;
    const float* t1 = ee1 + (size_t)bd[e] * D;
    uint* ag = agg_u + (size_t)dst[e] * D2;
    for (int d2 = lane; d2 < D2; d2 += 64) {
        uint hv = hs[d2];
        float2 a = *(const float2*)(t0 + d2 * 2);
        float2 b = *(const float2*)(t1 + d2 * 2);
        float lo = bf2f((ushort)(hv & 0xffffu)) + a.x + b.x;
        float hi = bf2f((ushort)(hv >> 16))     + a.y + b.y;
        atomic_add_bf16x2(ag + d2, lo, hi);
    }
}

// ---------------------------------------------------------------- BN fold prep
__global__ void prep_bn_kernel(
    const float* __restrict__ b2, const float* __restrict__ gamma,
    const float* __restrict__ beta, const float* __restrict__ mean,
    const float* __restrict__ var, float* __restrict__ scale2,
    float* __restrict__ shift2, int n)
{
    int i = blockIdx.x * blockDim.x + threadIdx.x;
    if (i >= n) return;
    float s = gamma[i] * rsqrtf(var[i] + BN_EPS);
    scale2[i] = s;
    shift2[i] = (b2[i] - mean[i]) * s + beta[i];
}

// ---------------------------------------------------------------- weight conversion
// W (f32, row-major [K,N]) -> hi/lo bf16 in MFMA-tile-linear layout:
// flat pos = (((nt*KS + ks)*4 + kg)*128 + c)*8 + j ; element W[k= ks*32+kg*8+j][n= nt*128+c]
// zero-padded for k>=K or n>=N. hi = bf16(w); lo = bf16(w - f32(hi))  => B-side ~f32 accurate.
__global__ __launch_bounds__(256) void conv_w_kernel(
    const float* __restrict__ W1, const float* __restrict__ W2,
    ushort* __restrict__ w1hi, ushort* __restrict__ w1lo,
    ushort* __restrict__ w2hi, ushort* __restrict__ w2lo)
{
    int i = blockIdx.x * blockDim.x + threadIdx.x;
    const int PER = P1 + P2;
    if (i >= NLAYERS * PER) return;
    int l = i / PER;
    int r = i - l * PER;
    float v;
    ushort *phi, *plo;
    if (r < P1) {
        int pos = r;
        int j = pos & 7, c = (pos >> 3) & 127, kg = (pos >> 10) & 3;
        int rest = pos >> 12;               // [0, NT1*KS1)
        int ks = rest % KS1, nt = rest / KS1;
        int k = ks * 32 + kg * 8 + j, n = nt * 128 + c;
        v = (k < D && n < HD) ? W1[(size_t)l * D * HD + (size_t)k * HD + n] : 0.f;
        phi = w1hi + (size_t)l * P1 + pos;
        plo = w1lo + (size_t)l * P1 + pos;
    } else {
        int pos = r - P1;
        int j = pos & 7, c = (pos >> 3) & 127, kg = (pos >> 10) & 3;
        int rest = pos >> 12;               // [0, NT2*KS2)
        int ks = rest % KS2, nt = rest / KS2;
        int k = ks * 32 + kg * 8 + j, n = nt * 128 + c;
        v = (k < HD && n < D) ? W2[(size_t)l * HD * D + (size_t)k * D + n] : 0.f;
        phi = w2hi + (size_t)l * P2 + pos;
        plo = w2lo + (size_t)l * P2 + pos;
    }
    ushort hi = f2bf(v);
    float  res = v - bf2f(hi);
    *phi = hi;
    *plo = f2bf(res);
}

// ---------------------------------------------------------------- MFMA GEMM + epilogue
// C[M,Ncols](bf16) = epi(A[M,K](bf16) @ (Bhi+Blo))  ; epi: y = dot*scale[c]+shift[c]; opt relu
// 128x128 tile, 4 waves (2x2), BK=32, reg-staged double-buffered LDS.
// LDS layout per operand: [kgroup(4)][idx(128)][8 bf16] -> conflict-free quarter-wave b128 reads.
// B is pre-tiled in global exactly in LDS order (8KB contiguous per kstep per ntile).
template<bool HAS_SCALE, bool RELU>
__global__ __launch_bounds__(256) void mfma_gemm_kernel(
    const ushort* __restrict__ A, int ldA, int M,
    const uint4* __restrict__ Bhi, const uint4* __restrict__ Blo, int KS,
    const float* __restrict__ scale, const float* __restrict__ shift,
    ushort* __restrict__ C, int ldC, int Ncols)
{
    __shared__ uint4 lds[2][1536];   // per buf: A[0..511], Bhi[512..1023], Blo[1024..1535]
    int t = threadIdx.x;
    int lane = t & 63;
    int wid = t >> 6;
    int wm = wid >> 1, wn = wid & 1;      // 2x2 wave grid, each wave 64x64 out
    int m0 = blockIdx.x * 128;
    int nt = blockIdx.y;

    int arow = t & 127;
    int akg0 = t >> 7;                    // this thread stages kgroups akg0 and akg0+2
    const char* abase = (const char*)A + (size_t)(m0 + arow) * (size_t)(ldA * 2) + akg0 * 16;
    const uint4* bhi_blk = Bhi + (size_t)nt * KS * 512;
    const uint4* blo_blk = Blo + (size_t)nt * KS * 512;

    f32x4 acc[4][4];
#pragma unroll
    for (int mi = 0; mi < 4; ++mi)
#pragma unroll
        for (int ni = 0; ni < 4; ++ni) {
            f32x4 z = {0.f, 0.f, 0.f, 0.f};
            acc[mi][ni] = z;
        }

    uint4 rA0, rA1, rB0, rB1, rC0, rC1;
    auto load_tiles = [&](int ks) {
        const char* p = abase + (size_t)ks * 64;
        uint2 x0 = *(const uint2*)(p);
        uint2 x1 = *(const uint2*)(p + 8);
        rA0 = make_uint4(x0.x, x0.y, x1.x, x1.y);
        uint2 y0 = *(const uint2*)(p + 32);
        uint2 y1 = *(const uint2*)(p + 40);
        rA1 = make_uint4(y0.x, y0.y, y1.x, y1.y);
        rB0 = bhi_blk[(size_t)ks * 512 + t];
        rB1 = bhi_blk[(size_t)ks * 512 + t + 256];
        rC0 = blo_blk[(size_t)ks * 512 + t];
        rC1 = blo_blk[(size_t)ks * 512 + t + 256];
    };
    auto write_tiles = [&](int buf) {
        uint4* d = lds[buf];
        d[t] = rA0;  d[t + 256] = rA1;          // A slots: kg*128+row = t / t+256
        d[512 + t] = rB0;  d[512 + t + 256] = rB1;
        d[1024 + t] = rC0; d[1024 + t + 256] = rC1;
    };

    // prologue
    load_tiles(0);
    write_tiles(0);
    __syncthreads();

    int arid = (lane >> 4) * 128 + wm * 64 + (lane & 15);
    int brid = (lane >> 4) * 128 + wn * 64 + (lane & 15);

    for (int ks = 0; ks < KS; ++ks) {
        bool more = (ks + 1 < KS);
        if (more) load_tiles(ks + 1);

        const short8v* lp = (const short8v*)lds[ks & 1];
        short8v a0 = lp[arid];
        short8v a1 = lp[arid + 16];
        short8v a2 = lp[arid + 32];
        short8v a3 = lp[arid + 48];
#pragma unroll
        for (int ni = 0; ni < 4; ++ni) {
            short8v bh = lp[512 + brid + ni * 16];
            short8v bl = lp[1024 + brid + ni * 16];
            acc[0][ni] = __builtin_amdgcn_mfma_f32_16x16x32_bf16(a0, bh, acc[0][ni], 0, 0, 0);
            acc[1][ni] = __builtin_amdgcn_mfma_f32_16x16x32_bf16(a1, bh, acc[1][ni], 0, 0, 0);
            acc[2][ni] = __builtin_amdgcn_mfma_f32_16x16x32_bf16(a2, bh, acc[2][ni], 0, 0, 0);
            acc[3][ni] = __builtin_amdgcn_mfma_f32_16x16x32_bf16(a3, bh, acc[3][ni], 0, 0, 0);
            acc[0][ni] = __builtin_amdgcn_mfma_f32_16x16x32_bf16(a0, bl, acc[0][ni], 0, 0, 0);
            acc[1][ni] = __builtin_amdgcn_mfma_f32_16x16x32_bf16(a1, bl, acc[1][ni], 0, 0, 0);
            acc[2][ni] = __builtin_amdgcn_mfma_f32_16x16x32_bf16(a2, bl, acc[2][ni], 0, 0, 0);
            acc[3][ni] = __builtin_amdgcn_mfma_f32_16x16x32_bf16(a3, bl, acc[3][ni], 0, 0, 0);
        }
        if (more) write_tiles((ks + 1) & 1);
        __syncthreads();
    }

    // epilogue: D mapping col=lane&15, row=(lane>>4)*4+reg  (m89-verified)
#pragma unroll
    for (int ni = 0; ni < 4; ++ni) {
        int col = nt * 128 + wn * 64 + ni * 16 + (lane & 15);
        if (col < Ncols) {
            float sc = HAS_SCALE ? scale[col] : 1.f;
            float sh = shift[col];
#pragma unroll
            for (int mi = 0; mi < 4; ++mi) {
                int rbase = m0 + wm * 64 + mi * 16 + (lane >> 4) * 4;
                f32x4 v = acc[mi][ni];
#pragma unroll
                for (int r = 0; r < 4; ++r) {
                    int row = rbase + r;
                    if (row < M) {
                        float y = v[r] * sc + sh;
                        if (RELU) y = fmaxf(y, 0.f);
                        C[(size_t)row * ldC + col] = f2bf(y);
                    }
                }
            }
        }
    }
}

// ---------------------------------------------------------------- avg pool
__global__ __launch_bounds__(320) void pool_kernel(
    const ushort* __restrict__ h, const int* __restrict__ gid,
    float* __restrict__ gavg, int N)
{
    int g = blockIdx.x;
    int lo = 0, hi = N;
    while (lo < hi) { int mid = (lo + hi) >> 1; if (gid[mid] < g) lo = mid + 1; else hi = mid; }
    int start = lo;
    lo = start; hi = N;
    while (lo < hi) { int mid = (lo + hi) >> 1; if (gid[mid] <= g) lo = mid + 1; else hi = mid; }
    int end = lo;
    int d = threadIdx.x;
    if (d >= D) return;
    float s = 0.f;
    for (int i = start; i < end; ++i) s += bf2f(h[(size_t)i * D + d]);
    float cnt = (float)(end - start);
    gavg[(size_t)g * D + d] = s / fmaxf(cnt, 1.f);
}

// ---------------------------------------------------------------- head
__global__ __launch_bounds__(256) void head_kernel(
    const float* __restrict__ gavg, const float* __restrict__ Wd,
    const float* __restrict__ bd, float* __restrict__ out)
{
    int g = blockIdx.x;
    int j = threadIdx.x;
    float s = bd[j];
    const float* gr = gavg + (size_t)g * D;
    for (int d = 0; d < D; ++d) s = fmaf(gr[d], Wd[(size_t)d * 256 + j], s);
    out[(size_t)g * 256 + j] = s;
}

// ================================================================ launch
extern "C" void kernel_launch(void* const* d_in, const int* in_sizes, int n_in,
                              void* d_out, int out_size, void* d_ws, size_t ws_size,
                              hipStream_t stream)
{
    const int*   atomic_number = (const int*)d_in[0];
    const int*   chirality     = (const int*)d_in[1];
    const int*   bond_type     = (const int*)d_in[2];
    const int*   bond_dir      = (const int*)d_in[3];
    const int*   src           = (const int*)d_in[4];
    const int*   dst           = (const int*)d_in[5];
    const int*   graph_ids     = (const int*)d_in[6];
    const float* node_emb0     = (const float*)d_in[8];
    const float* node_emb1     = (const float*)d_in[9];
    const float* edge_emb0     = (const float*)d_in[10];
    const float* edge_emb1     = (const float*)d_in[11];
    const float* W1            = (const float*)d_in[12];
    const float* b1            = (const float*)d_in[13];
    const float* W2            = (const float*)d_in[14];
    const float* b2            = (const float*)d_in[15];
    const float* bn_gamma      = (const float*)d_in[16];
    const float* bn_beta       = (const float*)d_in[17];
    const float* bn_mean       = (const float*)d_in[18];
    const float* bn_var        = (const float*)d_in[19];
    const float* Wd            = (const float*)d_in[20];
    const float* bd            = (const float*)d_in[21];

    int N = in_sizes[0];
    int E = in_sizes[2];
    int G = out_size / 256;
    float* out = (float*)d_out;

    // ---- ws layout ----
    char* ws = (char*)d_ws;
    size_t offs = 0;
    auto take = [&](size_t nbytes) -> char* {
        char* p = ws + offs;
        offs += (nbytes + 255) & ~(size_t)255;
        return p;
    };
    ushort* w1hi = (ushort*)take((size_t)NLAYERS * P1 * 2);
    ushort* w1lo = (ushort*)take((size_t)NLAYERS * P1 * 2);
    ushort* w2hi = (ushort*)take((size_t)NLAYERS * P2 * 2);
    ushort* w2lo = (ushort*)take((size_t)NLAYERS * P2 * 2);
    ushort* h      = (ushort*)take((size_t)N * D * 2);
    ushort* agg    = (ushort*)take((size_t)N * D * 2);
    float*  gavg   = (float*)take((size_t)G * D * 4);
    float*  scale2 = (float*)take((size_t)NLAYERS * D * 4);
    float*  shift2 = (float*)take((size_t)NLAYERS * D * 4);

    // hidden: adaptive chunk, +128KB guard (K-pad overrun reads up to ~77KB past last row)
    size_t avail = ws_size > offs ? ws_size - offs : 0;
    size_t guard = 131072 + 512;
    long max_rows = avail > guard ? (long)((avail - guard) / ((size_t)HD * 2)) : 0;
    int chunk;
    if (max_rows >= N) chunk = N;
    else {
        chunk = (int)((max_rows / 128) * 128);
        if (chunk < 128) chunk = 128;
    }
    ushort* hidden = (ushort*)take((size_t)chunk * HD * 2 + guard);

    // tiny prep
    prep_bn_kernel<<<(NLAYERS * D + 255) / 256, 256, 0, stream>>>(
        b2, bn_gamma, bn_beta, bn_mean, bn_var, scale2, shift2, NLAYERS * D);
    {
        int T = NLAYERS * (P1 + P2);
        conv_w_kernel<<<(T + 255) / 256, 256, 0, stream>>>(W1, W2, w1hi, w1lo, w2hi, w2lo);
    }
    embed_kernel<<<(N + 3) / 4, 256, 0, stream>>>(
        atomic_number, chirality, node_emb0, node_emb1, (uint*)h, N);

    long agg_u4 = (long)N * D2 / 4;
    int zgrid = (int)((agg_u4 + 255) / 256);
    if (zgrid > 4096) zgrid = 4096;

    for (int l = 0; l < NLAYERS; ++l) {
        zero_kernel<<<zgrid, 256, 0, stream>>>((uint4*)agg, agg_u4);
        message_kernel<<<(E + 3) / 4, 256, 0, stream>>>(
            (const uint*)h,
            edge_emb0 + (size_t)l * 6 * D,
            edge_emb1 + (size_t)l * 3 * D,
            bond_type, bond_dir, src, dst, (uint*)agg, E);

        for (int r0 = 0; r0 < N; r0 += chunk) {
            int cr = N - r0 < chunk ? N - r0 : chunk;
            dim3 g1((cr + 127) / 128, NT1);
            dim3 g2((cr + 127) / 128, NT2);
            // hidden = relu(agg_chunk @ W1[l] + b1[l])
            mfma_gemm_kernel<false, true><<<g1, 256, 0, stream>>>(
                agg + (size_t)r0 * D, D, cr,
                (const uint4*)(w1hi + (size_t)l * P1), (const uint4*)(w1lo + (size_t)l * P1), KS1,
                nullptr, b1 + (size_t)l * HD,
                hidden, HD, HD);
            // h_chunk = BN(hidden @ W2[l] + b2[l]) (+relu unless last layer)
            if (l < NLAYERS - 1)
                mfma_gemm_kernel<true, true><<<g2, 256, 0, stream>>>(
                    hidden, HD, cr,
                    (const uint4*)(w2hi + (size_t)l * P2), (const uint4*)(w2lo + (size_t)l * P2), KS2,
                    scale2 + (size_t)l * D, shift2 + (size_t)l * D,
                    h + (size_t)r0 * D, D, D);
            else
                mfma_gemm_kernel<true, false><<<g2, 256, 0, stream>>>(
                    hidden, HD, cr,
                    (const uint4*)(w2hi + (size_t)l * P2), (const uint4*)(w2lo + (size_t)l * P2), KS2,
                    scale2 + (size_t)l * D, shift2 + (size_t)l * D,
                    h + (size_t)r0 * D, D, D);
        }
    }

    pool_kernel<<<G, 320, 0, stream>>>(h, graph_ids, gavg, N);
    head_kernel<<<G, 256, 0, stream>>>(gavg, Wd, bd, out);
}

// Round 6
// 3897.222 us; speedup vs baseline: 5.0338x; 1.5559x over previous
//
#include <hip/hip_runtime.h>
#include <hip/hip_bf16.h>
#include <hip/hip_fp16.h>

#define D 300
#define D2 150          // f16 pairs per row
#define HD 600
#define NLAYERS 5
#define BN_EPS 1e-5f

// GEMM1: K=300->Kp=320 (KS1=10 ksteps), N=600->Np=640 (NT1=5 col tiles)
// GEMM2: K=600->Kp=640 (KS2=20),        N=300->Np=384 (NT2=3)
#define KS1 10
#define NT1 5
#define KS2 20
#define NT2 3
#define P1 (NT1*KS1*4096)   // 204800 elems per layer (w1 tiled)
#define P2 (NT2*KS2*4096)   // 245760 elems per layer (w2 tiled)

#define SCAN_BLK 1024       // elems per scan block (256 thr x 4); N <= 262144

typedef _Float16 f16x8 __attribute__((ext_vector_type(8)));
typedef __attribute__((ext_vector_type(4))) float f32x4;

// ---------------------------------------------------------------- f16 helpers
__device__ inline ushort f2h(float x) {
    __half h = __float2half(x);
    return *reinterpret_cast<ushort*>(&h);
}
__device__ inline float h2f(ushort u) {
    __half h;
    *reinterpret_cast<ushort*>(&h) = u;
    return __half2float(h);
}
__device__ inline uint pack2h(float lo, float hi) {
    return (uint)f2h(lo) | ((uint)f2h(hi) << 16);
}

// ---------------------------------------------------------------- zero fill
__global__ __launch_bounds__(256) void zero_kernel(uint4* __restrict__ p, long n4)
{
    long i = (long)blockIdx.x * blockDim.x + threadIdx.x;
    long stride = (long)gridDim.x * blockDim.x;
    uint4 z = make_uint4(0u, 0u, 0u, 0u);
    for (; i < n4; i += stride) p[i] = z;
}

// ---------------------------------------------------------------- embed (h f16)
__global__ __launch_bounds__(256) void embed_kernel(
    const int* __restrict__ an, const int* __restrict__ ch,
    const float* __restrict__ e0, const float* __restrict__ e1,
    uint* __restrict__ h_u, int N)
{
    int node = blockIdx.x * 4 + (threadIdx.x >> 6);
    if (node >= N) return;
    int lane = threadIdx.x & 63;
    const float* r0 = e0 + (size_t)an[node] * D;
    const float* r1 = e1 + (size_t)ch[node] * D;
    uint* hr = h_u + (size_t)node * D2;
    for (int d2 = lane; d2 < D2; d2 += 64) {
        float2 a = *(const float2*)(r0 + d2 * 2);
        float2 b = *(const float2*)(r1 + d2 * 2);
        hr[d2] = pack2h(a.x + b.x, a.y + b.y);
    }
}

// ---------------------------------------------------------------- CSR build (once; graph is layer-invariant)
__global__ __launch_bounds__(256) void count_kernel(
    const int* __restrict__ dst, int* __restrict__ deg, int E)
{
    int e = blockIdx.x * 256 + threadIdx.x;
    if (e < E) atomicAdd(&deg[dst[e]], 1);
}

__global__ __launch_bounds__(256) void scan_part_kernel(
    const int* __restrict__ deg, int* __restrict__ part, int N)
{
    __shared__ int sm[256];
    int b = blockIdx.x, t = threadIdx.x;
    int base = b * SCAN_BLK + t * 4;
    int s = 0;
#pragma unroll
    for (int j = 0; j < 4; ++j) { int i = base + j; if (i < N) s += deg[i]; }
    sm[t] = s;
    __syncthreads();
    for (int off = 128; off > 0; off >>= 1) {
        if (t < off) sm[t] += sm[t + off];
        __syncthreads();
    }
    if (t == 0) part[b] = sm[0];
}

__global__ __launch_bounds__(256) void scan_top_kernel(int* __restrict__ part, int NB)
{
    __shared__ int sm[256];
    int t = threadIdx.x;
    int own = (t < NB) ? part[t] : 0;
    sm[t] = own;
    __syncthreads();
    for (int off = 1; off < 256; off <<= 1) {
        int u = (t >= off) ? sm[t - off] : 0;
        __syncthreads();
        sm[t] += u;
        __syncthreads();
    }
    if (t < NB) part[t] = sm[t] - own;   // exclusive
}

__global__ __launch_bounds__(256) void scan_write_kernel(
    const int* __restrict__ deg, const int* __restrict__ part,
    int* __restrict__ offsets, int* __restrict__ cursor, int N, int E)
{
    __shared__ int sm[256];
    int b = blockIdx.x, t = threadIdx.x;
    int base = b * SCAN_BLK + t * 4;
    int v[4], s = 0;
#pragma unroll
    for (int j = 0; j < 4; ++j) { int i = base + j; v[j] = (i < N) ? deg[i] : 0; s += v[j]; }
    int own = s;
    sm[t] = s;
    __syncthreads();
    for (int off = 1; off < 256; off <<= 1) {
        int u = (t >= off) ? sm[t - off] : 0;
        __syncthreads();
        sm[t] += u;
        __syncthreads();
    }
    int ex = sm[t] - own + part[b];
#pragma unroll
    for (int j = 0; j < 4; ++j) {
        int i = base + j;
        if (i < N) { offsets[i] = ex; cursor[i] = ex; ex += v[j]; }
    }
    if (b == 0 && t == 0) offsets[N] = E;
}

__global__ __launch_bounds__(256) void scatter_kernel(
    const int* __restrict__ dst, int* __restrict__ cursor,
    int* __restrict__ csr, int E)
{
    int e = blockIdx.x * 256 + threadIdx.x;
    if (e < E) {
        int pos = atomicAdd(&cursor[dst[e]], 1);
        csr[pos] = e;
    }
}

// ---------------------------------------------------------------- per-layer aggregation (gather, no atomics)
// agg[v,:] = sum_{e in in(v)} h[src[e],:] + ee0[bt[e],:] + ee1[bd[e],:]
__global__ __launch_bounds__(256) void aggregate_kernel(
    const uint* __restrict__ h_u,
    const float* __restrict__ ee0, const float* __restrict__ ee1,
    const int* __restrict__ bt, const int* __restrict__ bd,
    const int* __restrict__ src,
    const int* __restrict__ offsets, const int* __restrict__ csr,
    uint* __restrict__ agg_u, int N)
{
    int v = blockIdx.x * 4 + (threadIdx.x >> 6);
    if (v >= N) return;
    int lane = threadIdx.x & 63;
    int p0 = offsets[v], p1 = offsets[v + 1];
    float ax[3] = {0.f, 0.f, 0.f}, ay[3] = {0.f, 0.f, 0.f};
    for (int p = p0; p < p1; ++p) {
        int e = csr[p];
        int s = src[e], tb = bt[e], db = bd[e];
        const uint*  hr = h_u + (size_t)s * D2;
        const float* r0 = ee0 + (size_t)tb * D;
        const float* r1 = ee1 + (size_t)db * D;
#pragma unroll
        for (int it = 0; it < 3; ++it) {
            int d2 = lane + it * 64;
            if (d2 < D2) {
                uint hv = hr[d2];
                float2 a = *(const float2*)(r0 + d2 * 2);
                float2 b = *(const float2*)(r1 + d2 * 2);
                ax[it] += h2f((ushort)(hv & 0xffffu)) + a.x + b.x;
                ay[it] += h2f((ushort)(hv >> 16))     + a.y + b.y;
            }
        }
    }
    uint* ag = agg_u + (size_t)v * D2;
#pragma unroll
    for (int it = 0; it < 3; ++it) {
        int d2 = lane + it * 64;
        if (d2 < D2) ag[d2] = pack2h(ax[it], ay[it]);
    }
}

// ---------------------------------------------------------------- BN fold prep
__global__ void prep_bn_kernel(
    const float* __restrict__ b2, const float* __restrict__ gamma,
    const float* __restrict__ beta, const float* __restrict__ mean,
    const float* __restrict__ var, float* __restrict__ scale2,
    float* __restrict__ shift2, int n)
{
    int i = blockIdx.x * blockDim.x + threadIdx.x;
    if (i >= n) return;
    float s = gamma[i] * rsqrtf(var[i] + BN_EPS);
    scale2[i] = s;
    shift2[i] = (b2[i] - mean[i]) * s + beta[i];
}

// ---------------------------------------------------------------- weight conversion (f32 -> f16, MFMA-tile-linear)
// flat pos = (((nt*KS + ks)*4 + kg)*128 + c)*8 + j ; element W[k= ks*32+kg*8+j][n= nt*128+c]
__global__ __launch_bounds__(256) void conv_w_kernel(
    const float* __restrict__ W1, const float* __restrict__ W2,
    ushort* __restrict__ w1h, ushort* __restrict__ w2h)
{
    int i = blockIdx.x * blockDim.x + threadIdx.x;
    const int PER = P1 + P2;
    if (i >= NLAYERS * PER) return;
    int l = i / PER;
    int r = i - l * PER;
    float v;
    ushort* ph;
    if (r < P1) {
        int pos = r;
        int j = pos & 7, c = (pos >> 3) & 127, kg = (pos >> 10) & 3;
        int rest = pos >> 12;
        int ks = rest % KS1, nt = rest / KS1;
        int k = ks * 32 + kg * 8 + j, n = nt * 128 + c;
        v = (k < D && n < HD) ? W1[(size_t)l * D * HD + (size_t)k * HD + n] : 0.f;
        ph = w1h + (size_t)l * P1 + pos;
    } else {
        int pos = r - P1;
        int j = pos & 7, c = (pos >> 3) & 127, kg = (pos >> 10) & 3;
        int rest = pos >> 12;
        int ks = rest % KS2, nt = rest / KS2;
        int k = ks * 32 + kg * 8 + j, n = nt * 128 + c;
        v = (k < HD && n < D) ? W2[(size_t)l * HD * D + (size_t)k * D + n] : 0.f;
        ph = w2h + (size_t)l * P2 + pos;
    }
    *ph = f2h(v);
}

// ---------------------------------------------------------------- MFMA GEMM + epilogue (f16 single)
// C[M,Ncols](f16) = epi(A[M,K](f16) @ B(f16 tiled)); epi: y = dot*scale[c]+shift[c]; opt relu
// 128x128 tile, 4 waves (2x2), BK=32, reg-staged double-buffered LDS (2 x 32KB).
template<bool HAS_SCALE, bool RELU>
__global__ __launch_bounds__(256) void mfma_gemm_kernel(
    const ushort* __restrict__ A, int ldA, int M,
    const uint4* __restrict__ B, int KS,
    const float* __restrict__ scale, const float* __restrict__ shift,
    ushort* __restrict__ C, int ldC, int Ncols)
{
    __shared__ uint4 lds[2][1024];   // per buf: A[0..511], B[512..1023]
    int t = threadIdx.x;
    int lane = t & 63;
    int wid = t >> 6;
    int wm = wid >> 1, wn = wid & 1;      // 2x2 wave grid, each wave 64x64 out
    int m0 = blockIdx.x * 128;
    int nt = blockIdx.y;

    int arow = t & 127;
    int akg0 = t >> 7;                    // stages kgroups akg0 and akg0+2
    const char* abase = (const char*)A + (size_t)(m0 + arow) * (size_t)(ldA * 2) + akg0 * 16;
    const uint4* b_blk = B + (size_t)nt * KS * 512;

    f32x4 acc[4][4];
#pragma unroll
    for (int mi = 0; mi < 4; ++mi)
#pragma unroll
        for (int ni = 0; ni < 4; ++ni) {
            f32x4 z = {0.f, 0.f, 0.f, 0.f};
            acc[mi][ni] = z;
        }

    uint4 rA0, rA1, rB0, rB1;
    auto load_tiles = [&](int ks) {
        const char* p = abase + (size_t)ks * 64;
        uint2 x0 = *(const uint2*)(p);
        uint2 x1 = *(const uint2*)(p + 8);
        rA0 = make_uint4(x0.x, x0.y, x1.x, x1.y);
        uint2 y0 = *(const uint2*)(p + 32);
        uint2 y1 = *(const uint2*)(p + 40);
        rA1 = make_uint4(y0.x, y0.y, y1.x, y1.y);
        rB0 = b_blk[(size_t)ks * 512 + t];
        rB1 = b_blk[(size_t)ks * 512 + t + 256];
    };
    auto write_tiles = [&](int buf) {
        uint4* d = lds[buf];
        d[t] = rA0;  d[t + 256] = rA1;          // A slot: kg*128+row
        d[512 + t] = rB0;  d[512 + t + 256] = rB1;
    };

    load_tiles(0);
    write_tiles(0);
    __syncthreads();

    int arid = (lane >> 4) * 128 + wm * 64 + (lane & 15);
    int brid = (lane >> 4) * 128 + wn * 64 + (lane & 15);

    for (int ks = 0; ks < KS; ++ks) {
        bool more = (ks + 1 < KS);
        if (more) load_tiles(ks + 1);

        const f16x8* lp = (const f16x8*)lds[ks & 1];
        f16x8 a0 = lp[arid];
        f16x8 a1 = lp[arid + 16];
        f16x8 a2 = lp[arid + 32];
        f16x8 a3 = lp[arid + 48];
#pragma unroll
        for (int ni = 0; ni < 4; ++ni) {
            f16x8 bh = lp[512 + brid + ni * 16];
            acc[0][ni] = __builtin_amdgcn_mfma_f32_16x16x32_f16(a0, bh, acc[0][ni], 0, 0, 0);
            acc[1][ni] = __builtin_amdgcn_mfma_f32_16x16x32_f16(a1, bh, acc[1][ni], 0, 0, 0);
            acc[2][ni] = __builtin_amdgcn_mfma_f32_16x16x32_f16(a2, bh, acc[2][ni], 0, 0, 0);
            acc[3][ni] = __builtin_amdgcn_mfma_f32_16x16x32_f16(a3, bh, acc[3][ni], 0, 0, 0);
        }
        if (more) write_tiles((ks + 1) & 1);
        __syncthreads();
    }

    // epilogue: D mapping col=lane&15, row=(lane>>4)*4+reg
#pragma unroll
    for (int ni = 0; ni < 4; ++ni) {
        int col = nt * 128 + wn * 64 + ni * 16 + (lane & 15);
        if (col < Ncols) {
            float sc = HAS_SCALE ? scale[col] : 1.f;
            float sh = shift[col];
#pragma unroll
            for (int mi = 0; mi < 4; ++mi) {
                int rbase = m0 + wm * 64 + mi * 16 + (lane >> 4) * 4;
                f32x4 v = acc[mi][ni];
#pragma unroll
                for (int r = 0; r < 4; ++r) {
                    int row = rbase + r;
                    if (row < M) {
                        float y = v[r] * sc + sh;
                        if (RELU) y = fmaxf(y, 0.f);
                        C[(size_t)row * ldC + col] = f2h(y);
                    }
                }
            }
        }
    }
}

// ---------------------------------------------------------------- avg pool
__global__ __launch_bounds__(320) void pool_kernel(
    const ushort* __restrict__ h, const int* __restrict__ gid,
    float* __restrict__ gavg, int N)
{
    int g = blockIdx.x;
    int lo = 0, hi = N;
    while (lo < hi) { int mid = (lo + hi) >> 1; if (gid[mid] < g) lo = mid + 1; else hi = mid; }
    int start = lo;
    lo = start; hi = N;
    while (lo < hi) { int mid = (lo + hi) >> 1; if (gid[mid] <= g) lo = mid + 1; else hi = mid; }
    int end = lo;
    int d = threadIdx.x;
    if (d >= D) return;
    float s = 0.f;
    for (int i = start; i < end; ++i) s += h2f(h[(size_t)i * D + d]);
    float cnt = (float)(end - start);
    gavg[(size_t)g * D + d] = s / fmaxf(cnt, 1.f);
}

// ---------------------------------------------------------------- head
__global__ __launch_bounds__(256) void head_kernel(
    const float* __restrict__ gavg, const float* __restrict__ Wd,
    const float* __restrict__ bd, float* __restrict__ out)
{
    int g = blockIdx.x;
    int j = threadIdx.x;
    float s = bd[j];
    const float* gr = gavg + (size_t)g * D;
    for (int d = 0; d < D; ++d) s = fmaf(gr[d], Wd[(size_t)d * 256 + j], s);
    out[(size_t)g * 256 + j] = s;
}

// ================================================================ launch
extern "C" void kernel_launch(void* const* d_in, const int* in_sizes, int n_in,
                              void* d_out, int out_size, void* d_ws, size_t ws_size,
                              hipStream_t stream)
{
    const int*   atomic_number = (const int*)d_in[0];
    const int*   chirality     = (const int*)d_in[1];
    const int*   bond_type     = (const int*)d_in[2];
    const int*   bond_dir      = (const int*)d_in[3];
    const int*   src           = (const int*)d_in[4];
    const int*   dst           = (const int*)d_in[5];
    const int*   graph_ids     = (const int*)d_in[6];
    const float* node_emb0     = (const float*)d_in[8];
    const float* node_emb1     = (const float*)d_in[9];
    const float* edge_emb0     = (const float*)d_in[10];
    const float* edge_emb1     = (const float*)d_in[11];
    const float* W1            = (const float*)d_in[12];
    const float* b1            = (const float*)d_in[13];
    const float* W2            = (const float*)d_in[14];
    const float* b2            = (const float*)d_in[15];
    const float* bn_gamma      = (const float*)d_in[16];
    const float* bn_beta       = (const float*)d_in[17];
    const float* bn_mean       = (const float*)d_in[18];
    const float* bn_var        = (const float*)d_in[19];
    const float* Wd            = (const float*)d_in[20];
    const float* bd            = (const float*)d_in[21];

    int N = in_sizes[0];
    int E = in_sizes[2];
    int G = out_size / 256;
    float* out = (float*)d_out;

    // ---- ws layout ----
    char* ws = (char*)d_ws;
    size_t offs = 0;
    auto take = [&](size_t nbytes) -> char* {
        char* p = ws + offs;
        offs += (nbytes + 255) & ~(size_t)255;
        return p;
    };
    ushort* w1h    = (ushort*)take((size_t)NLAYERS * P1 * 2);
    ushort* w2h    = (ushort*)take((size_t)NLAYERS * P2 * 2);
    ushort* h      = (ushort*)take((size_t)N * D * 2);
    ushort* agg    = (ushort*)take((size_t)N * D * 2);
    int*    deg    = (int*)take((size_t)N * 4);
    int*    offsets= (int*)take((size_t)(N + 1) * 4);
    int*    cursor = (int*)take((size_t)N * 4);
    int*    csr    = (int*)take((size_t)E * 4);
    int*    part   = (int*)take((size_t)256 * 4);
    float*  gavg   = (float*)take((size_t)G * D * 4);
    float*  scale2 = (float*)take((size_t)NLAYERS * D * 4);
    float*  shift2 = (float*)take((size_t)NLAYERS * D * 4);

    // hidden: adaptive chunk + guard for unguarded A-tile overrun reads (<=160 rows x 1200B)
    size_t avail = ws_size > offs ? ws_size - offs : 0;
    size_t guard = 196608;
    long max_rows = avail > guard ? (long)((avail - guard) / ((size_t)HD * 2)) : 0;
    int chunk;
    if (max_rows >= N) chunk = N;
    else {
        chunk = (int)((max_rows / 128) * 128);
        if (chunk < 128) chunk = 128;
    }
    ushort* hidden = (ushort*)take((size_t)chunk * HD * 2 + guard);

    // ---- tiny prep ----
    prep_bn_kernel<<<(NLAYERS * D + 255) / 256, 256, 0, stream>>>(
        b2, bn_gamma, bn_beta, bn_mean, bn_var, scale2, shift2, NLAYERS * D);
    {
        int T = NLAYERS * (P1 + P2);
        conv_w_kernel<<<(T + 255) / 256, 256, 0, stream>>>(W1, W2, w1h, w2h);
    }
    embed_kernel<<<(N + 3) / 4, 256, 0, stream>>>(
        atomic_number, chirality, node_emb0, node_emb1, (uint*)h, N);

    // ---- CSR build (once; layer-invariant) ----
    int NB = (N + SCAN_BLK - 1) / SCAN_BLK;   // <=256 for N<=262144
    zero_kernel<<<(int)(((size_t)N + 1023) / 1024), 256, 0, stream>>>((uint4*)deg, (long)N / 4);
    count_kernel<<<(E + 255) / 256, 256, 0, stream>>>(dst, deg, E);
    scan_part_kernel<<<NB, 256, 0, stream>>>(deg, part, N);
    scan_top_kernel<<<1, 256, 0, stream>>>(part, NB);
    scan_write_kernel<<<NB, 256, 0, stream>>>(deg, part, offsets, cursor, N, E);
    scatter_kernel<<<(E + 255) / 256, 256, 0, stream>>>(dst, cursor, csr, E);

    for (int l = 0; l < NLAYERS; ++l) {
        aggregate_kernel<<<(N + 3) / 4, 256, 0, stream>>>(
            (const uint*)h,
            edge_emb0 + (size_t)l * 6 * D,
            edge_emb1 + (size_t)l * 3 * D,
            bond_type, bond_dir, src, offsets, csr, (uint*)agg, N);

        for (int r0 = 0; r0 < N; r0 += chunk) {
            int cr = N - r0 < chunk ? N - r0 : chunk;
            dim3 g1((cr + 127) / 128, NT1);
            dim3 g2((cr + 127) / 128, NT2);
            // hidden = relu(agg_chunk @ W1[l] + b1[l])
            mfma_gemm_kernel<false, true><<<g1, 256, 0, stream>>>(
                agg + (size_t)r0 * D, D, cr,
                (const uint4*)(w1h + (size_t)l * P1), KS1,
                nullptr, b1 + (size_t)l * HD,
                hidden, HD, HD);
            // h_chunk = BN(hidden @ W2[l] + b2[l]) (+relu unless last layer)
            if (l < NLAYERS - 1)
                mfma_gemm_kernel<true, true><<<g2, 256, 0, stream>>>(
                    hidden, HD, cr,
                    (const uint4*)(w2h + (size_t)l * P2), KS2,
                    scale2 + (size_t)l * D, shift2 + (size_t)l * D,
                    h + (size_t)r0 * D, D, D);
            else
                mfma_gemm_kernel<true, false><<<g2, 256, 0, stream>>>(
                    hidden, HD, cr,
                    (const uint4*)(w2h + (size_t)l * P2), KS2,
                    scale2 + (size_t)l * D, shift2 + (size_t)l * D,
                    h + (size_t)r0 * D, D, D);
        }
    }

    pool_kernel<<<G, 320, 0, stream>>>(h, graph_ids, gavg, N);
    head_kernel<<<G, 256, 0, stream>>>(gavg, Wd, bd, out);
}

// Round 7
// 2345.053 us; speedup vs baseline: 8.3657x; 1.6619x over previous
//
#include <hip/hip_runtime.h>
#include <hip/hip_bf16.h>
#include <hip/hip_fp16.h>

#define D 300
#define D2 150          // f16 pairs per row
#define HD 600
#define NLAYERS 5
#define BN_EPS 1e-5f

// GEMM1: K=300->320 (KS1=10), N=600->640. GEMM2: K=600->640 (KS2=20), N=300->384.
#define KS1 10
#define NT1 5
#define KS2 20
#define NT2 3
#define P1 (NT1*KS1*4096)   // 204800 f16 per layer (w1 tiled)
#define P2 (NT2*KS2*4096)   // 245760 f16 per layer (w2 tiled)

#define SCAN_BLK 1024

typedef _Float16 f16x8 __attribute__((ext_vector_type(8)));
typedef __attribute__((ext_vector_type(4))) float f32x4;

// ---------------------------------------------------------------- f16 helpers
__device__ inline ushort f2h(float x) {
    __half h = __float2half(x);
    return *reinterpret_cast<ushort*>(&h);
}
__device__ inline float h2f(ushort u) {
    __half h;
    *reinterpret_cast<ushort*>(&h) = u;
    return __half2float(h);
}
__device__ inline uint pack2h(float lo, float hi) {
    return (uint)f2h(lo) | ((uint)f2h(hi) << 16);
}

// ---------------------------------------------------------------- zero fill
__global__ __launch_bounds__(256) void zero_kernel(uint4* __restrict__ p, long n4)
{
    long i = (long)blockIdx.x * blockDim.x + threadIdx.x;
    long stride = (long)gridDim.x * blockDim.x;
    uint4 z = make_uint4(0u, 0u, 0u, 0u);
    for (; i < n4; i += stride) p[i] = z;
}

// ---------------------------------------------------------------- embed (h f16)
__global__ __launch_bounds__(256) void embed_kernel(
    const int* __restrict__ an, const int* __restrict__ ch,
    const float* __restrict__ e0, const float* __restrict__ e1,
    uint* __restrict__ h_u, int N)
{
    int node = blockIdx.x * 4 + (threadIdx.x >> 6);
    if (node >= N) return;
    int lane = threadIdx.x & 63;
    const float* r0 = e0 + (size_t)an[node] * D;
    const float* r1 = e1 + (size_t)ch[node] * D;
    uint* hr = h_u + (size_t)node * D2;
    for (int d2 = lane; d2 < D2; d2 += 64) {
        float2 a = *(const float2*)(r0 + d2 * 2);
        float2 b = *(const float2*)(r1 + d2 * 2);
        hr[d2] = pack2h(a.x + b.x, a.y + b.y);
    }
}

// ---------------------------------------------------------------- CSR build (once)
__global__ __launch_bounds__(256) void count_kernel(
    const int* __restrict__ dst, int* __restrict__ deg, int E)
{
    int e = blockIdx.x * 256 + threadIdx.x;
    if (e < E) atomicAdd(&deg[dst[e]], 1);
}

__global__ __launch_bounds__(256) void scan_part_kernel(
    const int* __restrict__ deg, int* __restrict__ part, int N)
{
    __shared__ int sm[256];
    int b = blockIdx.x, t = threadIdx.x;
    int base = b * SCAN_BLK + t * 4;
    int s = 0;
#pragma unroll
    for (int j = 0; j < 4; ++j) { int i = base + j; if (i < N) s += deg[i]; }
    sm[t] = s;
    __syncthreads();
    for (int off = 128; off > 0; off >>= 1) {
        if (t < off) sm[t] += sm[t + off];
        __syncthreads();
    }
    if (t == 0) part[b] = sm[0];
}

__global__ __launch_bounds__(256) void scan_top_kernel(int* __restrict__ part, int NB)
{
    __shared__ int sm[256];
    int t = threadIdx.x;
    int own = (t < NB) ? part[t] : 0;
    sm[t] = own;
    __syncthreads();
    for (int off = 1; off < 256; off <<= 1) {
        int u = (t >= off) ? sm[t - off] : 0;
        __syncthreads();
        sm[t] += u;
        __syncthreads();
    }
    if (t < NB) part[t] = sm[t] - own;   // exclusive
}

__global__ __launch_bounds__(256) void scan_write_kernel(
    const int* __restrict__ deg, const int* __restrict__ part,
    int* __restrict__ offsets, int* __restrict__ cursor, int N, int E)
{
    __shared__ int sm[256];
    int b = blockIdx.x, t = threadIdx.x;
    int base = b * SCAN_BLK + t * 4;
    int v[4], s = 0;
#pragma unroll
    for (int j = 0; j < 4; ++j) { int i = base + j; v[j] = (i < N) ? deg[i] : 0; s += v[j]; }
    int own = s;
    sm[t] = s;
    __syncthreads();
    for (int off = 1; off < 256; off <<= 1) {
        int u = (t >= off) ? sm[t - off] : 0;
        __syncthreads();
        sm[t] += u;
        __syncthreads();
    }
    int ex = sm[t] - own + part[b];
#pragma unroll
    for (int j = 0; j < 4; ++j) {
        int i = base + j;
        if (i < N) { offsets[i] = ex; cursor[i] = ex; ex += v[j]; }
    }
    if (b == 0 && t == 0) offsets[N] = E;
}

__global__ __launch_bounds__(256) void scatter_kernel(
    const int* __restrict__ dst, int* __restrict__ cursor,
    int* __restrict__ csr, int E)
{
    int e = blockIdx.x * 256 + threadIdx.x;
    if (e < E) {
        int pos = atomicAdd(&cursor[dst[e]], 1);
        csr[pos] = e;
    }
}

// ---------------------------------------------------------------- per-layer aggregation
__global__ __launch_bounds__(256) void aggregate_kernel(
    const uint* __restrict__ h_u,
    const float* __restrict__ ee0, const float* __restrict__ ee1,
    const int* __restrict__ bt, const int* __restrict__ bd,
    const int* __restrict__ src,
    const int* __restrict__ offsets, const int* __restrict__ csr,
    uint* __restrict__ agg_u, int N)
{
    int v = blockIdx.x * 4 + (threadIdx.x >> 6);
    if (v >= N) return;
    int lane = threadIdx.x & 63;
    int p0 = offsets[v], p1 = offsets[v + 1];
    float ax[3] = {0.f, 0.f, 0.f}, ay[3] = {0.f, 0.f, 0.f};
    for (int p = p0; p < p1; ++p) {
        int e = csr[p];
        int s = src[e], tb = bt[e], db = bd[e];
        const uint*  hr = h_u + (size_t)s * D2;
        const float* r0 = ee0 + (size_t)tb * D;
        const float* r1 = ee1 + (size_t)db * D;
#pragma unroll
        for (int it = 0; it < 3; ++it) {
            int d2 = lane + it * 64;
            if (d2 < D2) {
                uint hv = hr[d2];
                float2 a = *(const float2*)(r0 + d2 * 2);
                float2 b = *(const float2*)(r1 + d2 * 2);
                ax[it] += h2f((ushort)(hv & 0xffffu)) + a.x + b.x;
                ay[it] += h2f((ushort)(hv >> 16))     + a.y + b.y;
            }
        }
    }
    uint* ag = agg_u + (size_t)v * D2;
#pragma unroll
    for (int it = 0; it < 3; ++it) {
        int d2 = lane + it * 64;
        if (d2 < D2) ag[d2] = pack2h(ax[it], ay[it]);
    }
}

// ---------------------------------------------------------------- BN fold prep
__global__ void prep_bn_kernel(
    const float* __restrict__ b2, const float* __restrict__ gamma,
    const float* __restrict__ beta, const float* __restrict__ mean,
    const float* __restrict__ var, float* __restrict__ scale2,
    float* __restrict__ shift2, int n)
{
    int i = blockIdx.x * blockDim.x + threadIdx.x;
    if (i >= n) return;
    float s = gamma[i] * rsqrtf(var[i] + BN_EPS);
    scale2[i] = s;
    shift2[i] = (b2[i] - mean[i]) * s + beta[i];
}

// ---------------------------------------------------------------- weight conversion (f32 -> f16, MFMA-tile-linear)
// flat pos = (((nt*KS + ks)*4 + kg)*128 + c)*8 + j ; element W[k=ks*32+kg*8+j][n=nt*128+c]
__global__ __launch_bounds__(256) void conv_w_kernel(
    const float* __restrict__ W1, const float* __restrict__ W2,
    ushort* __restrict__ w1h, ushort* __restrict__ w2h)
{
    int i = blockIdx.x * blockDim.x + threadIdx.x;
    const int PER = P1 + P2;
    if (i >= NLAYERS * PER) return;
    int l = i / PER;
    int r = i - l * PER;
    float v;
    ushort* ph;
    if (r < P1) {
        int pos = r;
        int j = pos & 7, c = (pos >> 3) & 127, kg = (pos >> 10) & 3;
        int rest = pos >> 12;
        int ks = rest % KS1, nt = rest / KS1;
        int k = ks * 32 + kg * 8 + j, n = nt * 128 + c;
        v = (k < D && n < HD) ? W1[(size_t)l * D * HD + (size_t)k * HD + n] : 0.f;
        ph = w1h + (size_t)l * P1 + pos;
    } else {
        int pos = r - P1;
        int j = pos & 7, c = (pos >> 3) & 127, kg = (pos >> 10) & 3;
        int rest = pos >> 12;
        int ks = rest % KS2, nt = rest / KS2;
        int k = ks * 32 + kg * 8 + j, n = nt * 128 + c;
        v = (k < HD && n < D) ? W2[(size_t)l * HD * D + (size_t)k * D + n] : 0.f;
        ph = w2h + (size_t)l * P2 + pos;
    }
    *ph = f2h(v);
}

// ---------------------------------------------------------------- fused MLP layer kernel
// block = 64 node rows, 512 threads (8 waves).
// Phase 1: A-tile (agg 64x320, zero-padded) -> LDS [ks10][kg4][row64][8]
// Phase 2: GEMM1 hidden = relu(A @ W1 + b1); W1 fragments streamed from global
//          (pre-tiled, L2-resident), 1-step register prefetch. hidden -> LDS
//          [ks20][kg4][row64][8] (A-operand layout for GEMM2).
// Phase 3: GEMM2 out = BN(hidden @ W2) (+relu); write global h (f16).
template<bool RELU2>
__global__ __launch_bounds__(512) void fused_mlp_kernel(
    const ushort* __restrict__ Ain,    // agg [N,300] f16
    const uint4* __restrict__ B1,      // W1 tiled, layer base
    const uint4* __restrict__ B2,      // W2 tiled, layer base
    const float* __restrict__ bias1,   // [600]
    const float* __restrict__ scale2,  // [300]
    const float* __restrict__ shift2,  // [300]
    ushort* __restrict__ Hout,         // h [N,300] f16
    int M)
{
    __shared__ ushort ldsA[KS1 * 4 * 64 * 8];   // 20480 halves, 40 KB
    __shared__ ushort ldsH[KS2 * 4 * 64 * 8];   // 40960 halves, 80 KB

    int t = threadIdx.x;
    int lane = t & 63;
    int wid = t >> 6;                 // 0..7
    int lanelo = lane & 15;
    int kg = lane >> 4;
    int m0 = blockIdx.x * 64;

    // ---- Phase 1: A-tile load (64 rows x 80 uint2; c2>=75 -> zero K-pad) ----
    {
        const uint2* Ag = (const uint2*)Ain;
#pragma unroll
        for (int i = 0; i < 10; ++i) {
            int g = t + i * 512;               // [0,5120)
            int r = g / 80, c2 = g - r * 80;
            uint2 v = make_uint2(0u, 0u);
            if (c2 < 75 && (m0 + r) < M) v = Ag[(size_t)(m0 + r) * 75 + c2];
            int k0 = c2 * 4;
            int ks = k0 >> 5, g2 = (k0 >> 3) & 3, j = k0 & 7;
            ((uint2*)ldsA)[(((ks * 4 + g2) * 64 + r) * 8 + j) >> 2] = v;
        }
    }
    __syncthreads();

    // ---- Phase 2: GEMM1 (64x640), wave wid covers cols [wid*80, wid*80+80) ----
    {
        f32x4 acc[4][5];
#pragma unroll
        for (int mi = 0; mi < 4; ++mi)
#pragma unroll
            for (int ni = 0; ni < 5; ++ni) {
                f32x4 z = {0.f, 0.f, 0.f, 0.f};
                acc[mi][ni] = z;
            }

        int addrb[5];
#pragma unroll
        for (int ni = 0; ni < 5; ++ni) {
            int col = wid * 80 + ni * 16 + lanelo;
            int nt = col >> 7, c = col & 127;
            addrb[ni] = nt * (KS1 * 512) + kg * 128 + c;
        }

        uint4 bn[5];
#pragma unroll
        for (int ni = 0; ni < 5; ++ni) bn[ni] = B1[addrb[ni]];

        const f16x8* ap = (const f16x8*)ldsA;
#pragma unroll
        for (int ks = 0; ks < KS1; ++ks) {
            uint4 bc[5];
#pragma unroll
            for (int ni = 0; ni < 5; ++ni) bc[ni] = bn[ni];
            if (ks + 1 < KS1) {
#pragma unroll
                for (int ni = 0; ni < 5; ++ni) bn[ni] = B1[addrb[ni] + (ks + 1) * 512];
            }
            int ab = (ks * 4 + kg) * 64 + lanelo;
            f16x8 a0 = ap[ab];
            f16x8 a1 = ap[ab + 16];
            f16x8 a2 = ap[ab + 32];
            f16x8 a3 = ap[ab + 48];
#pragma unroll
            for (int ni = 0; ni < 5; ++ni) {
                f16x8 b = *(const f16x8*)&bc[ni];
                acc[0][ni] = __builtin_amdgcn_mfma_f32_16x16x32_f16(a0, b, acc[0][ni], 0, 0, 0);
                acc[1][ni] = __builtin_amdgcn_mfma_f32_16x16x32_f16(a1, b, acc[1][ni], 0, 0, 0);
                acc[2][ni] = __builtin_amdgcn_mfma_f32_16x16x32_f16(a2, b, acc[2][ni], 0, 0, 0);
                acc[3][ni] = __builtin_amdgcn_mfma_f32_16x16x32_f16(a3, b, acc[3][ni], 0, 0, 0);
            }
        }

        // epilogue: +bias, relu, -> ldsH in GEMM2 A-operand layout
#pragma unroll
        for (int ni = 0; ni < 5; ++ni) {
            int col = wid * 80 + ni * 16 + lanelo;
            float bias = (col < HD) ? bias1[col] : 0.f;
            int ks2 = col >> 5, g2 = (col >> 3) & 3, j2 = col & 7;
            int base = ((ks2 * 4 + g2) * 64) * 8 + j2;
#pragma unroll
            for (int mi = 0; mi < 4; ++mi) {
                int r0 = mi * 16 + kg * 4;
#pragma unroll
                for (int r = 0; r < 4; ++r) {
                    float y = acc[mi][ni][r] + bias;
                    y = fmaxf(y, 0.f);
                    ldsH[base + (r0 + r) * 8] = f2h(y);
                }
            }
        }
    }
    __syncthreads();

    // ---- Phase 3: GEMM2 (64x384), wave wid covers cols [wid*48, wid*48+48) ----
    {
        f32x4 acc[4][3];
#pragma unroll
        for (int mi = 0; mi < 4; ++mi)
#pragma unroll
            for (int ni = 0; ni < 3; ++ni) {
                f32x4 z = {0.f, 0.f, 0.f, 0.f};
                acc[mi][ni] = z;
            }

        int addrb[3];
#pragma unroll
        for (int ni = 0; ni < 3; ++ni) {
            int col = wid * 48 + ni * 16 + lanelo;
            int nt = col >> 7, c = col & 127;
            addrb[ni] = nt * (KS2 * 512) + kg * 128 + c;
        }

        uint4 bn[3];
#pragma unroll
        for (int ni = 0; ni < 3; ++ni) bn[ni] = B2[addrb[ni]];

        const f16x8* hp = (const f16x8*)ldsH;
#pragma unroll
        for (int ks = 0; ks < KS2; ++ks) {
            uint4 bc[3];
#pragma unroll
            for (int ni = 0; ni < 3; ++ni) bc[ni] = bn[ni];
            if (ks + 1 < KS2) {
#pragma unroll
                for (int ni = 0; ni < 3; ++ni) bn[ni] = B2[addrb[ni] + (ks + 1) * 512];
            }
            int ab = (ks * 4 + kg) * 64 + lanelo;
            f16x8 a0 = hp[ab];
            f16x8 a1 = hp[ab + 16];
            f16x8 a2 = hp[ab + 32];
            f16x8 a3 = hp[ab + 48];
#pragma unroll
            for (int ni = 0; ni < 3; ++ni) {
                f16x8 b = *(const f16x8*)&bc[ni];
                acc[0][ni] = __builtin_amdgcn_mfma_f32_16x16x32_f16(a0, b, acc[0][ni], 0, 0, 0);
                acc[1][ni] = __builtin_amdgcn_mfma_f32_16x16x32_f16(a1, b, acc[1][ni], 0, 0, 0);
                acc[2][ni] = __builtin_amdgcn_mfma_f32_16x16x32_f16(a2, b, acc[2][ni], 0, 0, 0);
                acc[3][ni] = __builtin_amdgcn_mfma_f32_16x16x32_f16(a3, b, acc[3][ni], 0, 0, 0);
            }
        }

        // epilogue: BN (+relu), write global h
#pragma unroll
        for (int ni = 0; ni < 3; ++ni) {
            int col = wid * 48 + ni * 16 + lanelo;
            if (col < D) {
                float sc = scale2[col];
                float sh = shift2[col];
#pragma unroll
                for (int mi = 0; mi < 4; ++mi) {
                    int rbase = m0 + mi * 16 + kg * 4;
#pragma unroll
                    for (int r = 0; r < 4; ++r) {
                        int row = rbase + r;
                        if (row < M) {
                            float y = acc[mi][ni][r] * sc + sh;
                            if (RELU2) y = fmaxf(y, 0.f);
                            Hout[(size_t)row * D + col] = f2h(y);
                        }
                    }
                }
            }
        }
    }
}

// ---------------------------------------------------------------- avg pool
__global__ __launch_bounds__(320) void pool_kernel(
    const ushort* __restrict__ h, const int* __restrict__ gid,
    float* __restrict__ gavg, int N)
{
    int g = blockIdx.x;
    int lo = 0, hi = N;
    while (lo < hi) { int mid = (lo + hi) >> 1; if (gid[mid] < g) lo = mid + 1; else hi = mid; }
    int start = lo;
    lo = start; hi = N;
    while (lo < hi) { int mid = (lo + hi) >> 1; if (gid[mid] <= g) lo = mid + 1; else hi = mid; }
    int end = lo;
    int d = threadIdx.x;
    if (d >= D) return;
    float s = 0.f;
    for (int i = start; i < end; ++i) s += h2f(h[(size_t)i * D + d]);
    float cnt = (float)(end - start);
    gavg[(size_t)g * D + d] = s / fmaxf(cnt, 1.f);
}

// ---------------------------------------------------------------- head
__global__ __launch_bounds__(256) void head_kernel(
    const float* __restrict__ gavg, const float* __restrict__ Wd,
    const float* __restrict__ bd, float* __restrict__ out)
{
    int g = blockIdx.x;
    int j = threadIdx.x;
    float s = bd[j];
    const float* gr = gavg + (size_t)g * D;
    for (int d = 0; d < D; ++d) s = fmaf(gr[d], Wd[(size_t)d * 256 + j], s);
    out[(size_t)g * 256 + j] = s;
}

// ================================================================ launch
extern "C" void kernel_launch(void* const* d_in, const int* in_sizes, int n_in,
                              void* d_out, int out_size, void* d_ws, size_t ws_size,
                              hipStream_t stream)
{
    const int*   atomic_number = (const int*)d_in[0];
    const int*   chirality     = (const int*)d_in[1];
    const int*   bond_type     = (const int*)d_in[2];
    const int*   bond_dir      = (const int*)d_in[3];
    const int*   src           = (const int*)d_in[4];
    const int*   dst           = (const int*)d_in[5];
    const int*   graph_ids     = (const int*)d_in[6];
    const float* node_emb0     = (const float*)d_in[8];
    const float* node_emb1     = (const float*)d_in[9];
    const float* edge_emb0     = (const float*)d_in[10];
    const float* edge_emb1     = (const float*)d_in[11];
    const float* W1            = (const float*)d_in[12];
    const float* b1            = (const float*)d_in[13];
    const float* W2            = (const float*)d_in[14];
    // d_in[15] b2 folded into BN shift
    const float* b2            = (const float*)d_in[15];
    const float* bn_gamma      = (const float*)d_in[16];
    const float* bn_beta       = (const float*)d_in[17];
    const float* bn_mean       = (const float*)d_in[18];
    const float* bn_var        = (const float*)d_in[19];
    const float* Wd            = (const float*)d_in[20];
    const float* bd            = (const float*)d_in[21];

    int N = in_sizes[0];
    int E = in_sizes[2];
    int G = out_size / 256;
    float* out = (float*)d_out;

    // ---- ws layout (no hidden buffer needed anymore) ----
    char* ws = (char*)d_ws;
    size_t offs = 0;
    auto take = [&](size_t nbytes) -> char* {
        char* p = ws + offs;
        offs += (nbytes + 255) & ~(size_t)255;
        return p;
    };
    ushort* w1h    = (ushort*)take((size_t)NLAYERS * P1 * 2);
    ushort* w2h    = (ushort*)take((size_t)NLAYERS * P2 * 2);
    ushort* h      = (ushort*)take((size_t)N * D * 2);
    ushort* agg    = (ushort*)take((size_t)N * D * 2);
    int*    deg    = (int*)take((size_t)N * 4);
    int*    offsets= (int*)take((size_t)(N + 1) * 4);
    int*    cursor = (int*)take((size_t)N * 4);
    int*    csr    = (int*)take((size_t)E * 4);
    int*    part   = (int*)take((size_t)256 * 4);
    float*  gavg   = (float*)take((size_t)G * D * 4);
    float*  scale2 = (float*)take((size_t)NLAYERS * D * 4);
    float*  shift2 = (float*)take((size_t)NLAYERS * D * 4);

    // ---- tiny prep ----
    prep_bn_kernel<<<(NLAYERS * D + 255) / 256, 256, 0, stream>>>(
        b2, bn_gamma, bn_beta, bn_mean, bn_var, scale2, shift2, NLAYERS * D);
    {
        int T = NLAYERS * (P1 + P2);
        conv_w_kernel<<<(T + 255) / 256, 256, 0, stream>>>(W1, W2, w1h, w2h);
    }
    embed_kernel<<<(N + 3) / 4, 256, 0, stream>>>(
        atomic_number, chirality, node_emb0, node_emb1, (uint*)h, N);

    // ---- CSR build (once; layer-invariant) ----
    int NB = (N + SCAN_BLK - 1) / SCAN_BLK;
    zero_kernel<<<(int)(((size_t)N + 1023) / 1024), 256, 0, stream>>>((uint4*)deg, (long)N / 4);
    count_kernel<<<(E + 255) / 256, 256, 0, stream>>>(dst, deg, E);
    scan_part_kernel<<<NB, 256, 0, stream>>>(deg, part, N);
    scan_top_kernel<<<1, 256, 0, stream>>>(part, NB);
    scan_write_kernel<<<NB, 256, 0, stream>>>(deg, part, offsets, cursor, N, E);
    scatter_kernel<<<(E + 255) / 256, 256, 0, stream>>>(dst, cursor, csr, E);

    int mlp_grid = (N + 63) / 64;
    for (int l = 0; l < NLAYERS; ++l) {
        aggregate_kernel<<<(N + 3) / 4, 256, 0, stream>>>(
            (const uint*)h,
            edge_emb0 + (size_t)l * 6 * D,
            edge_emb1 + (size_t)l * 3 * D,
            bond_type, bond_dir, src, offsets, csr, (uint*)agg, N);

        if (l < NLAYERS - 1)
            fused_mlp_kernel<true><<<mlp_grid, 512, 0, stream>>>(
                agg,
                (const uint4*)(w1h + (size_t)l * P1),
                (const uint4*)(w2h + (size_t)l * P2),
                b1 + (size_t)l * HD,
                scale2 + (size_t)l * D, shift2 + (size_t)l * D,
                h, N);
        else
            fused_mlp_kernel<false><<<mlp_grid, 512, 0, stream>>>(
                agg,
                (const uint4*)(w1h + (size_t)l * P1),
                (const uint4*)(w2h + (size_t)l * P2),
                b1 + (size_t)l * HD,
                scale2 + (size_t)l * D, shift2 + (size_t)l * D,
                h, N);
    }

    pool_kernel<<<G, 320, 0, stream>>>(h, graph_ids, gavg, N);
    head_kernel<<<G, 256, 0, stream>>>(gavg, Wd, bd, out);
}

// Round 8
// 1996.684 us; speedup vs baseline: 9.8253x; 1.1745x over previous
//
#include <hip/hip_runtime.h>
#include <hip/hip_bf16.h>
#include <hip/hip_fp16.h>

#define D 300
#define D2 150          // f16 pairs per row
#define HD 600
#define NLAYERS 5
#define BN_EPS 1e-5f

// GEMM1: K=300->320 (KS1=10), N=600->640. GEMM2: K=600->640 (KS2=20), N=300->384.
#define KS1 10
#define NT1 5
#define KS2 20
#define NT2 3
#define P1 (NT1*KS1*4096)   // 204800 f16 per layer (w1 tiled)
#define P2 (NT2*KS2*4096)   // 245760 f16 per layer (w2 tiled)

#define SCAN_BLK 1024

typedef _Float16 f16x8 __attribute__((ext_vector_type(8)));
typedef __attribute__((ext_vector_type(4))) float f32x4;

// ---------------------------------------------------------------- f16 helpers
__device__ inline ushort f2h(float x) {
    __half h = __float2half(x);
    return *reinterpret_cast<ushort*>(&h);
}
__device__ inline float h2f(ushort u) {
    __half h;
    *reinterpret_cast<ushort*>(&h) = u;
    return __half2float(h);
}
__device__ inline uint pack2h(float lo, float hi) {
    return (uint)f2h(lo) | ((uint)f2h(hi) << 16);
}

// ---------------------------------------------------------------- zero fill
__global__ __launch_bounds__(256) void zero_kernel(uint4* __restrict__ p, long n4)
{
    long i = (long)blockIdx.x * blockDim.x + threadIdx.x;
    long stride = (long)gridDim.x * blockDim.x;
    uint4 z = make_uint4(0u, 0u, 0u, 0u);
    for (; i < n4; i += stride) p[i] = z;
}

// ---------------------------------------------------------------- embed (h f16)
__global__ __launch_bounds__(256) void embed_kernel(
    const int* __restrict__ an, const int* __restrict__ ch,
    const float* __restrict__ e0, const float* __restrict__ e1,
    uint* __restrict__ h_u, int N)
{
    int node = blockIdx.x * 4 + (threadIdx.x >> 6);
    if (node >= N) return;
    int lane = threadIdx.x & 63;
    const float* r0 = e0 + (size_t)an[node] * D;
    const float* r1 = e1 + (size_t)ch[node] * D;
    uint* hr = h_u + (size_t)node * D2;
    for (int d2 = lane; d2 < D2; d2 += 64) {
        float2 a = *(const float2*)(r0 + d2 * 2);
        float2 b = *(const float2*)(r1 + d2 * 2);
        hr[d2] = pack2h(a.x + b.x, a.y + b.y);
    }
}

// ---------------------------------------------------------------- CSR build (once)
__global__ __launch_bounds__(256) void count_kernel(
    const int* __restrict__ dst, int* __restrict__ deg, int E)
{
    int e = blockIdx.x * 256 + threadIdx.x;
    if (e < E) atomicAdd(&deg[dst[e]], 1);
}

__global__ __launch_bounds__(256) void scan_part_kernel(
    const int* __restrict__ deg, int* __restrict__ part, int N)
{
    __shared__ int sm[256];
    int b = blockIdx.x, t = threadIdx.x;
    int base = b * SCAN_BLK + t * 4;
    int s = 0;
#pragma unroll
    for (int j = 0; j < 4; ++j) { int i = base + j; if (i < N) s += deg[i]; }
    sm[t] = s;
    __syncthreads();
    for (int off = 128; off > 0; off >>= 1) {
        if (t < off) sm[t] += sm[t + off];
        __syncthreads();
    }
    if (t == 0) part[b] = sm[0];
}

__global__ __launch_bounds__(256) void scan_top_kernel(int* __restrict__ part, int NB)
{
    __shared__ int sm[256];
    int t = threadIdx.x;
    int own = (t < NB) ? part[t] : 0;
    sm[t] = own;
    __syncthreads();
    for (int off = 1; off < 256; off <<= 1) {
        int u = (t >= off) ? sm[t - off] : 0;
        __syncthreads();
        sm[t] += u;
        __syncthreads();
    }
    if (t < NB) part[t] = sm[t] - own;   // exclusive
}

__global__ __launch_bounds__(256) void scan_write_kernel(
    const int* __restrict__ deg, const int* __restrict__ part,
    int* __restrict__ offsets, int* __restrict__ cursor, int N, int E)
{
    __shared__ int sm[256];
    int b = blockIdx.x, t = threadIdx.x;
    int base = b * SCAN_BLK + t * 4;
    int v[4], s = 0;
#pragma unroll
    for (int j = 0; j < 4; ++j) { int i = base + j; v[j] = (i < N) ? deg[i] : 0; s += v[j]; }
    int own = s;
    sm[t] = s;
    __syncthreads();
    for (int off = 1; off < 256; off <<= 1) {
        int u = (t >= off) ? sm[t - off] : 0;
        __syncthreads();
        sm[t] += u;
        __syncthreads();
    }
    int ex = sm[t] - own + part[b];
#pragma unroll
    for (int j = 0; j < 4; ++j) {
        int i = base + j;
        if (i < N) { offsets[i] = ex; cursor[i] = ex; ex += v[j]; }
    }
    if (b == 0 && t == 0) offsets[N] = E;
}

__global__ __launch_bounds__(256) void scatter_kernel(
    const int* __restrict__ dst, int* __restrict__ cursor,
    int* __restrict__ csr, int E)
{
    int e = blockIdx.x * 256 + threadIdx.x;
    if (e < E) {
        int pos = atomicAdd(&cursor[dst[e]], 1);
        csr[pos] = e;
    }
}

// ---------------------------------------------------------------- edge prep (once): CSR-ordered src + combo id
__global__ __launch_bounds__(256) void eprep_kernel(
    const int* __restrict__ csr, const int* __restrict__ src,
    const int* __restrict__ bt, const int* __restrict__ bd,
    int* __restrict__ esrc, unsigned char* __restrict__ ecomb, int E)
{
    int p = blockIdx.x * 256 + threadIdx.x;
    if (p < E) {
        int e = csr[p];
        esrc[p] = src[e];
        ecomb[p] = (unsigned char)(bt[e] * 3 + bd[e]);
    }
}

// ---------------------------------------------------------------- edge-emb combo table: etab[l][c=bt*3+bd][D] f16
__global__ __launch_bounds__(256) void etab_kernel(
    const float* __restrict__ ee0, const float* __restrict__ ee1,
    uint* __restrict__ etab)
{
    int i = blockIdx.x * 256 + threadIdx.x;
    const int total = NLAYERS * 18 * D2;
    if (i >= total) return;
    int d2 = i % D2;
    int rest = i / D2;
    int c = rest % 18, l = rest / 18;
    int btv = c / 3, bdv = c % 3;
    const float* r0 = ee0 + ((size_t)l * 6 + btv) * D + d2 * 2;
    const float* r1 = ee1 + ((size_t)l * 3 + bdv) * D + d2 * 2;
    etab[i] = pack2h(r0[0] + r1[0], r0[1] + r1[1]);
}

// ---------------------------------------------------------------- per-layer aggregation (gather, no atomics)
__global__ __launch_bounds__(256) void aggregate_kernel(
    const uint* __restrict__ h_u,
    const uint* __restrict__ etab_l,          // [18][D2] f16x2 for this layer
    const int* __restrict__ esrc, const unsigned char* __restrict__ ecomb,
    const int* __restrict__ offsets,
    uint* __restrict__ agg_u, int N)
{
    int v = blockIdx.x * 4 + (threadIdx.x >> 6);
    if (v >= N) return;
    int lane = threadIdx.x & 63;
    int p0 = offsets[v], p1 = offsets[v + 1];
    float ax[3] = {0.f, 0.f, 0.f}, ay[3] = {0.f, 0.f, 0.f};
    for (int p = p0; p < p1; ++p) {
        int s = esrc[p];
        int c = ecomb[p];
        const uint* hr = h_u + (size_t)s * D2;
        const uint* er = etab_l + c * D2;
#pragma unroll
        for (int it = 0; it < 3; ++it) {
            int d2 = lane + it * 64;
            if (d2 < D2) {
                uint hv = hr[d2];
                uint ev = er[d2];
                ax[it] += h2f((ushort)(hv & 0xffffu)) + h2f((ushort)(ev & 0xffffu));
                ay[it] += h2f((ushort)(hv >> 16))     + h2f((ushort)(ev >> 16));
            }
        }
    }
    uint* ag = agg_u + (size_t)v * D2;
#pragma unroll
    for (int it = 0; it < 3; ++it) {
        int d2 = lane + it * 64;
        if (d2 < D2) ag[d2] = pack2h(ax[it], ay[it]);
    }
}

// ---------------------------------------------------------------- BN fold prep
__global__ void prep_bn_kernel(
    const float* __restrict__ b2, const float* __restrict__ gamma,
    const float* __restrict__ beta, const float* __restrict__ mean,
    const float* __restrict__ var, float* __restrict__ scale2,
    float* __restrict__ shift2, int n)
{
    int i = blockIdx.x * blockDim.x + threadIdx.x;
    if (i >= n) return;
    float s = gamma[i] * rsqrtf(var[i] + BN_EPS);
    scale2[i] = s;
    shift2[i] = (b2[i] - mean[i]) * s + beta[i];
}

// ---------------------------------------------------------------- weight conversion (f32 -> f16, MFMA-tile-linear)
// flat pos = (((nt*KS + ks)*4 + kg)*128 + c)*8 + j ; element W[k=ks*32+kg*8+j][n=nt*128+c]
__global__ __launch_bounds__(256) void conv_w_kernel(
    const float* __restrict__ W1, const float* __restrict__ W2,
    ushort* __restrict__ w1h, ushort* __restrict__ w2h)
{
    int i = blockIdx.x * blockDim.x + threadIdx.x;
    const int PER = P1 + P2;
    if (i >= NLAYERS * PER) return;
    int l = i / PER;
    int r = i - l * PER;
    float v;
    ushort* ph;
    if (r < P1) {
        int pos = r;
        int j = pos & 7, c = (pos >> 3) & 127, kg = (pos >> 10) & 3;
        int rest = pos >> 12;
        int ks = rest % KS1, nt = rest / KS1;
        int k = ks * 32 + kg * 8 + j, n = nt * 128 + c;
        v = (k < D && n < HD) ? W1[(size_t)l * D * HD + (size_t)k * HD + n] : 0.f;
        ph = w1h + (size_t)l * P1 + pos;
    } else {
        int pos = r - P1;
        int j = pos & 7, c = (pos >> 3) & 127, kg = (pos >> 10) & 3;
        int rest = pos >> 12;
        int ks = rest % KS2, nt = rest / KS2;
        int k = ks * 32 + kg * 8 + j, n = nt * 128 + c;
        v = (k < HD && n < D) ? W2[(size_t)l * HD * D + (size_t)k * D + n] : 0.f;
        ph = w2h + (size_t)l * P2 + pos;
    }
    *ph = f2h(v);
}

// ---------------------------------------------------------------- fused MLP layer kernel
// block = 64 node rows, 512 threads (8 waves).
// ldsA (40KB, GEMM1 A-tile) and ldsH (80KB, hidden) are ALIASED: ldsA is dead
// after the GEMM1 MFMA loop (barrier), then the same space holds hidden.
// Total LDS 80KB -> 2 blocks/CU (was 120KB -> 1 block/CU).
template<bool RELU2>
__global__ __launch_bounds__(512, 4) void fused_mlp_kernel(
    const ushort* __restrict__ Ain,    // agg [N,300] f16
    const uint4* __restrict__ B1,      // W1 tiled, layer base
    const uint4* __restrict__ B2,      // W2 tiled, layer base
    const float* __restrict__ bias1,   // [600]
    const float* __restrict__ scale2,  // [300]
    const float* __restrict__ shift2,  // [300]
    ushort* __restrict__ Hout,         // h [N,300] f16
    int M)
{
    __shared__ ushort lds[KS2 * 4 * 64 * 8];    // 80 KB, aliased A-tile / hidden
    ushort* ldsA = lds;
    ushort* ldsH = lds;

    int t = threadIdx.x;
    int lane = t & 63;
    int wid = t >> 6;                 // 0..7
    int lanelo = lane & 15;
    int kg = lane >> 4;
    int m0 = blockIdx.x * 64;

    // ---- Phase 1: A-tile load (64 rows x 80 uint2; c2>=75 -> zero K-pad) ----
    {
        const uint2* Ag = (const uint2*)Ain;
#pragma unroll
        for (int i = 0; i < 10; ++i) {
            int g = t + i * 512;               // [0,5120)
            int r = g / 80, c2 = g - r * 80;
            uint2 v = make_uint2(0u, 0u);
            if (c2 < 75 && (m0 + r) < M) v = Ag[(size_t)(m0 + r) * 75 + c2];
            int k0 = c2 * 4;
            int ks = k0 >> 5, g2 = (k0 >> 3) & 3, j = k0 & 7;
            ((uint2*)ldsA)[(((ks * 4 + g2) * 64 + r) * 8 + j) >> 2] = v;
        }
    }
    __syncthreads();

    // ---- Phase 2: GEMM1 (64x640), wave wid covers cols [wid*80, wid*80+80) ----
    {
        f32x4 acc[4][5];
#pragma unroll
        for (int mi = 0; mi < 4; ++mi)
#pragma unroll
            for (int ni = 0; ni < 5; ++ni) {
                f32x4 z = {0.f, 0.f, 0.f, 0.f};
                acc[mi][ni] = z;
            }

        int addrb[5];
#pragma unroll
        for (int ni = 0; ni < 5; ++ni) {
            int col = wid * 80 + ni * 16 + lanelo;
            int nt = col >> 7, c = col & 127;
            addrb[ni] = nt * (KS1 * 512) + kg * 128 + c;
        }

        uint4 bn[5];
#pragma unroll
        for (int ni = 0; ni < 5; ++ni) bn[ni] = B1[addrb[ni]];

        const f16x8* ap = (const f16x8*)ldsA;
#pragma unroll
        for (int ks = 0; ks < KS1; ++ks) {
            uint4 bc[5];
#pragma unroll
            for (int ni = 0; ni < 5; ++ni) bc[ni] = bn[ni];
            if (ks + 1 < KS1) {
#pragma unroll
                for (int ni = 0; ni < 5; ++ni) bn[ni] = B1[addrb[ni] + (ks + 1) * 512];
            }
            int ab = (ks * 4 + kg) * 64 + lanelo;
            f16x8 a0 = ap[ab];
            f16x8 a1 = ap[ab + 16];
            f16x8 a2 = ap[ab + 32];
            f16x8 a3 = ap[ab + 48];
#pragma unroll
            for (int ni = 0; ni < 5; ++ni) {
                f16x8 b = *(const f16x8*)&bc[ni];
                acc[0][ni] = __builtin_amdgcn_mfma_f32_16x16x32_f16(a0, b, acc[0][ni], 0, 0, 0);
                acc[1][ni] = __builtin_amdgcn_mfma_f32_16x16x32_f16(a1, b, acc[1][ni], 0, 0, 0);
                acc[2][ni] = __builtin_amdgcn_mfma_f32_16x16x32_f16(a2, b, acc[2][ni], 0, 0, 0);
                acc[3][ni] = __builtin_amdgcn_mfma_f32_16x16x32_f16(a3, b, acc[3][ni], 0, 0, 0);
            }
        }

        // all waves must finish READING ldsA before we overwrite it with hidden
        __syncthreads();

        // epilogue: +bias, relu, -> ldsH in GEMM2 A-operand layout
#pragma unroll
        for (int ni = 0; ni < 5; ++ni) {
            int col = wid * 80 + ni * 16 + lanelo;
            float bias = (col < HD) ? bias1[col] : 0.f;
            int ks2 = col >> 5, g2 = (col >> 3) & 3, j2 = col & 7;
            int base = ((ks2 * 4 + g2) * 64) * 8 + j2;
#pragma unroll
            for (int mi = 0; mi < 4; ++mi) {
                int r0 = mi * 16 + kg * 4;
#pragma unroll
                for (int r = 0; r < 4; ++r) {
                    float y = acc[mi][ni][r] + bias;
                    y = fmaxf(y, 0.f);
                    ldsH[base + (r0 + r) * 8] = f2h(y);
                }
            }
        }
    }
    __syncthreads();

    // ---- Phase 3: GEMM2 (64x384), wave wid covers cols [wid*48, wid*48+48) ----
    {
        f32x4 acc[4][3];
#pragma unroll
        for (int mi = 0; mi < 4; ++mi)
#pragma unroll
            for (int ni = 0; ni < 3; ++ni) {
                f32x4 z = {0.f, 0.f, 0.f, 0.f};
                acc[mi][ni] = z;
            }

        int addrb[3];
#pragma unroll
        for (int ni = 0; ni < 3; ++ni) {
            int col = wid * 48 + ni * 16 + lanelo;
            int nt = col >> 7, c = col & 127;
            addrb[ni] = nt * (KS2 * 512) + kg * 128 + c;
        }

        uint4 bn[3];
#pragma unroll
        for (int ni = 0; ni < 3; ++ni) bn[ni] = B2[addrb[ni]];

        const f16x8* hp = (const f16x8*)ldsH;
#pragma unroll
        for (int ks = 0; ks < KS2; ++ks) {
            uint4 bc[3];
#pragma unroll
            for (int ni = 0; ni < 3; ++ni) bc[ni] = bn[ni];
            if (ks + 1 < KS2) {
#pragma unroll
                for (int ni = 0; ni < 3; ++ni) bn[ni] = B2[addrb[ni] + (ks + 1) * 512];
            }
            int ab = (ks * 4 + kg) * 64 + lanelo;
            f16x8 a0 = hp[ab];
            f16x8 a1 = hp[ab + 16];
            f16x8 a2 = hp[ab + 32];
            f16x8 a3 = hp[ab + 48];
#pragma unroll
            for (int ni = 0; ni < 3; ++ni) {
                f16x8 b = *(const f16x8*)&bc[ni];
                acc[0][ni] = __builtin_amdgcn_mfma_f32_16x16x32_f16(a0, b, acc[0][ni], 0, 0, 0);
                acc[1][ni] = __builtin_amdgcn_mfma_f32_16x16x32_f16(a1, b, acc[1][ni], 0, 0, 0);
                acc[2][ni] = __builtin_amdgcn_mfma_f32_16x16x32_f16(a2, b, acc[2][ni], 0, 0, 0);
                acc[3][ni] = __builtin_amdgcn_mfma_f32_16x16x32_f16(a3, b, acc[3][ni], 0, 0, 0);
            }
        }

        // epilogue: BN (+relu), write global h
#pragma unroll
        for (int ni = 0; ni < 3; ++ni) {
            int col = wid * 48 + ni * 16 + lanelo;
            if (col < D) {
                float sc = scale2[col];
                float sh = shift2[col];
#pragma unroll
                for (int mi = 0; mi < 4; ++mi) {
                    int rbase = m0 + mi * 16 + kg * 4;
#pragma unroll
                    for (int r = 0; r < 4; ++r) {
                        int row = rbase + r;
                        if (row < M) {
                            float y = acc[mi][ni][r] * sc + sh;
                            if (RELU2) y = fmaxf(y, 0.f);
                            Hout[(size_t)row * D + col] = f2h(y);
                        }
                    }
                }
            }
        }
    }
}

// ---------------------------------------------------------------- avg pool
__global__ __launch_bounds__(320) void pool_kernel(
    const ushort* __restrict__ h, const int* __restrict__ gid,
    float* __restrict__ gavg, int N)
{
    int g = blockIdx.x;
    int lo = 0, hi = N;
    while (lo < hi) { int mid = (lo + hi) >> 1; if (gid[mid] < g) lo = mid + 1; else hi = mid; }
    int start = lo;
    lo = start; hi = N;
    while (lo < hi) { int mid = (lo + hi) >> 1; if (gid[mid] <= g) lo = mid + 1; else hi = mid; }
    int end = lo;
    int d = threadIdx.x;
    if (d >= D) return;
    float s = 0.f;
    for (int i = start; i < end; ++i) s += h2f(h[(size_t)i * D + d]);
    float cnt = (float)(end - start);
    gavg[(size_t)g * D + d] = s / fmaxf(cnt, 1.f);
}

// ---------------------------------------------------------------- head
__global__ __launch_bounds__(256) void head_kernel(
    const float* __restrict__ gavg, const float* __restrict__ Wd,
    const float* __restrict__ bd, float* __restrict__ out)
{
    int g = blockIdx.x;
    int j = threadIdx.x;
    float s = bd[j];
    const float* gr = gavg + (size_t)g * D;
    for (int d = 0; d < D; ++d) s = fmaf(gr[d], Wd[(size_t)d * 256 + j], s);
    out[(size_t)g * 256 + j] = s;
}

// ================================================================ launch
extern "C" void kernel_launch(void* const* d_in, const int* in_sizes, int n_in,
                              void* d_out, int out_size, void* d_ws, size_t ws_size,
                              hipStream_t stream)
{
    const int*   atomic_number = (const int*)d_in[0];
    const int*   chirality     = (const int*)d_in[1];
    const int*   bond_type     = (const int*)d_in[2];
    const int*   bond_dir      = (const int*)d_in[3];
    const int*   src           = (const int*)d_in[4];
    const int*   dst           = (const int*)d_in[5];
    const int*   graph_ids     = (const int*)d_in[6];
    const float* node_emb0     = (const float*)d_in[8];
    const float* node_emb1     = (const float*)d_in[9];
    const float* edge_emb0     = (const float*)d_in[10];
    const float* edge_emb1     = (const float*)d_in[11];
    const float* W1            = (const float*)d_in[12];
    const float* b1            = (const float*)d_in[13];
    const float* W2            = (const float*)d_in[14];
    const float* b2            = (const float*)d_in[15];
    const float* bn_gamma      = (const float*)d_in[16];
    const float* bn_beta       = (const float*)d_in[17];
    const float* bn_mean       = (const float*)d_in[18];
    const float* bn_var        = (const float*)d_in[19];
    const float* Wd            = (const float*)d_in[20];
    const float* bd            = (const float*)d_in[21];

    int N = in_sizes[0];
    int E = in_sizes[2];
    int G = out_size / 256;
    float* out = (float*)d_out;

    // ---- ws layout ----
    char* ws = (char*)d_ws;
    size_t offs = 0;
    auto take = [&](size_t nbytes) -> char* {
        char* p = ws + offs;
        offs += (nbytes + 255) & ~(size_t)255;
        return p;
    };
    ushort* w1h    = (ushort*)take((size_t)NLAYERS * P1 * 2);
    ushort* w2h    = (ushort*)take((size_t)NLAYERS * P2 * 2);
    ushort* h      = (ushort*)take((size_t)N * D * 2);
    ushort* agg    = (ushort*)take((size_t)N * D * 2);
    int*    deg    = (int*)take((size_t)N * 4);
    int*    offsets= (int*)take((size_t)(N + 1) * 4);
    int*    cursor = (int*)take((size_t)N * 4);
    int*    csr    = (int*)take((size_t)E * 4);
    int*    esrc   = (int*)take((size_t)E * 4);
    unsigned char* ecomb = (unsigned char*)take((size_t)E);
    uint*   etab   = (uint*)take((size_t)NLAYERS * 18 * D2 * 4);
    int*    part   = (int*)take((size_t)256 * 4);
    float*  gavg   = (float*)take((size_t)G * D * 4);
    float*  scale2 = (float*)take((size_t)NLAYERS * D * 4);
    float*  shift2 = (float*)take((size_t)NLAYERS * D * 4);

    // ---- tiny prep ----
    prep_bn_kernel<<<(NLAYERS * D + 255) / 256, 256, 0, stream>>>(
        b2, bn_gamma, bn_beta, bn_mean, bn_var, scale2, shift2, NLAYERS * D);
    {
        int T = NLAYERS * (P1 + P2);
        conv_w_kernel<<<(T + 255) / 256, 256, 0, stream>>>(W1, W2, w1h, w2h);
    }
    etab_kernel<<<(NLAYERS * 18 * D2 + 255) / 256, 256, 0, stream>>>(
        edge_emb0, edge_emb1, etab);
    embed_kernel<<<(N + 3) / 4, 256, 0, stream>>>(
        atomic_number, chirality, node_emb0, node_emb1, (uint*)h, N);

    // ---- CSR build (once; layer-invariant) ----
    int NB = (N + SCAN_BLK - 1) / SCAN_BLK;
    zero_kernel<<<(int)(((size_t)N + 1023) / 1024), 256, 0, stream>>>((uint4*)deg, (long)N / 4);
    count_kernel<<<(E + 255) / 256, 256, 0, stream>>>(dst, deg, E);
    scan_part_kernel<<<NB, 256, 0, stream>>>(deg, part, N);
    scan_top_kernel<<<1, 256, 0, stream>>>(part, NB);
    scan_write_kernel<<<NB, 256, 0, stream>>>(deg, part, offsets, cursor, N, E);
    scatter_kernel<<<(E + 255) / 256, 256, 0, stream>>>(dst, cursor, csr, E);
    eprep_kernel<<<(E + 255) / 256, 256, 0, stream>>>(csr, src, bond_type, bond_dir, esrc, ecomb, E);

    int mlp_grid = (N + 63) / 64;
    for (int l = 0; l < NLAYERS; ++l) {
        aggregate_kernel<<<(N + 3) / 4, 256, 0, stream>>>(
            (const uint*)h,
            etab + (size_t)l * 18 * D2,
            esrc, ecomb, offsets, (uint*)agg, N);

        if (l < NLAYERS - 1)
            fused_mlp_kernel<true><<<mlp_grid, 512, 0, stream>>>(
                agg,
                (const uint4*)(w1h + (size_t)l * P1),
                (const uint4*)(w2h + (size_t)l * P2),
                b1 + (size_t)l * HD,
                scale2 + (size_t)l * D, shift2 + (size_t)l * D,
                h, N);
        else
            fused_mlp_kernel<false><<<mlp_grid, 512, 0, stream>>>(
                agg,
                (const uint4*)(w1h + (size_t)l * P1),
                (const uint4*)(w2h + (size_t)l * P2),
                b1 + (size_t)l * HD,
                scale2 + (size_t)l * D, shift2 + (size_t)l * D,
                h, N);
    }

    pool_kernel<<<G, 320, 0, stream>>>(h, graph_ids, gavg, N);
    head_kernel<<<G, 256, 0, stream>>>(gavg, Wd, bd, out);
}

// Round 9
// 1840.585 us; speedup vs baseline: 10.6585x; 1.0848x over previous
//
#include <hip/hip_runtime.h>
#include <hip/hip_bf16.h>
#include <hip/hip_fp16.h>

#define D 300
#define D2 150          // f16 pairs per row
#define HD 600
#define NLAYERS 5
#define BN_EPS 1e-5f

// GEMM1: K=300->320 (KS1=10), N=600->640. GEMM2: K=600->640 (KS2=20), N=300->384.
#define KS1 10
#define NT1 5
#define KS2 20
#define NT2 3
#define P1 (NT1*KS1*4096)   // 204800 f16 per layer (w1 tiled)
#define P2 (NT2*KS2*4096)   // 245760 f16 per layer (w2 tiled)

#define SCAN_BLK 1024

typedef _Float16 f16x8 __attribute__((ext_vector_type(8)));
typedef __attribute__((ext_vector_type(4))) float f32x4;

// ---------------------------------------------------------------- f16 helpers
__device__ inline ushort f2h(float x) {
    __half h = __float2half(x);
    return *reinterpret_cast<ushort*>(&h);
}
__device__ inline float h2f(ushort u) {
    __half h;
    *reinterpret_cast<ushort*>(&h) = u;
    return __half2float(h);
}
__device__ inline uint pack2h(float lo, float hi) {
    return (uint)f2h(lo) | ((uint)f2h(hi) << 16);
}

// ---------------------------------------------------------------- zero fill
__global__ __launch_bounds__(256) void zero_kernel(uint4* __restrict__ p, long n4)
{
    long i = (long)blockIdx.x * blockDim.x + threadIdx.x;
    long stride = (long)gridDim.x * blockDim.x;
    uint4 z = make_uint4(0u, 0u, 0u, 0u);
    for (; i < n4; i += stride) p[i] = z;
}

// ---------------------------------------------------------------- embed (h f16)
__global__ __launch_bounds__(256) void embed_kernel(
    const int* __restrict__ an, const int* __restrict__ ch,
    const float* __restrict__ e0, const float* __restrict__ e1,
    uint* __restrict__ h_u, int N)
{
    int node = blockIdx.x * 4 + (threadIdx.x >> 6);
    if (node >= N) return;
    int lane = threadIdx.x & 63;
    const float* r0 = e0 + (size_t)an[node] * D;
    const float* r1 = e1 + (size_t)ch[node] * D;
    uint* hr = h_u + (size_t)node * D2;
    for (int d2 = lane; d2 < D2; d2 += 64) {
        float2 a = *(const float2*)(r0 + d2 * 2);
        float2 b = *(const float2*)(r1 + d2 * 2);
        hr[d2] = pack2h(a.x + b.x, a.y + b.y);
    }
}

// ---------------------------------------------------------------- CSR build (once)
__global__ __launch_bounds__(256) void count_kernel(
    const int* __restrict__ dst, int* __restrict__ deg, int E)
{
    int e = blockIdx.x * 256 + threadIdx.x;
    if (e < E) atomicAdd(&deg[dst[e]], 1);
}

__global__ __launch_bounds__(256) void scan_part_kernel(
    const int* __restrict__ deg, int* __restrict__ part, int N)
{
    __shared__ int sm[256];
    int b = blockIdx.x, t = threadIdx.x;
    int base = b * SCAN_BLK + t * 4;
    int s = 0;
#pragma unroll
    for (int j = 0; j < 4; ++j) { int i = base + j; if (i < N) s += deg[i]; }
    sm[t] = s;
    __syncthreads();
    for (int off = 128; off > 0; off >>= 1) {
        if (t < off) sm[t] += sm[t + off];
        __syncthreads();
    }
    if (t == 0) part[b] = sm[0];
}

__global__ __launch_bounds__(256) void scan_top_kernel(int* __restrict__ part, int NB)
{
    __shared__ int sm[256];
    int t = threadIdx.x;
    int own = (t < NB) ? part[t] : 0;
    sm[t] = own;
    __syncthreads();
    for (int off = 1; off < 256; off <<= 1) {
        int u = (t >= off) ? sm[t - off] : 0;
        __syncthreads();
        sm[t] += u;
        __syncthreads();
    }
    if (t < NB) part[t] = sm[t] - own;   // exclusive
}

__global__ __launch_bounds__(256) void scan_write_kernel(
    const int* __restrict__ deg, const int* __restrict__ part,
    int* __restrict__ offsets, int* __restrict__ cursor, int N, int E)
{
    __shared__ int sm[256];
    int b = blockIdx.x, t = threadIdx.x;
    int base = b * SCAN_BLK + t * 4;
    int v[4], s = 0;
#pragma unroll
    for (int j = 0; j < 4; ++j) { int i = base + j; v[j] = (i < N) ? deg[i] : 0; s += v[j]; }
    int own = s;
    sm[t] = s;
    __syncthreads();
    for (int off = 1; off < 256; off <<= 1) {
        int u = (t >= off) ? sm[t - off] : 0;
        __syncthreads();
        sm[t] += u;
        __syncthreads();
    }
    int ex = sm[t] - own + part[b];
#pragma unroll
    for (int j = 0; j < 4; ++j) {
        int i = base + j;
        if (i < N) { offsets[i] = ex; cursor[i] = ex; ex += v[j]; }
    }
    if (b == 0 && t == 0) offsets[N] = E;
}

__global__ __launch_bounds__(256) void scatter_kernel(
    const int* __restrict__ dst, int* __restrict__ cursor,
    int* __restrict__ csr, int E)
{
    int e = blockIdx.x * 256 + threadIdx.x;
    if (e < E) {
        int pos = atomicAdd(&cursor[dst[e]], 1);
        csr[pos] = e;
    }
}

// ---------------------------------------------------------------- edge prep (once): CSR-ordered src + combo id
__global__ __launch_bounds__(256) void eprep_kernel(
    const int* __restrict__ csr, const int* __restrict__ src,
    const int* __restrict__ bt, const int* __restrict__ bd,
    int* __restrict__ esrc, unsigned char* __restrict__ ecomb, int E)
{
    int p = blockIdx.x * 256 + threadIdx.x;
    if (p < E) {
        int e = csr[p];
        esrc[p] = src[e];
        ecomb[p] = (unsigned char)(bt[e] * 3 + bd[e]);
    }
}

// ---------------------------------------------------------------- edge-emb combo table: etab[l][c=bt*3+bd][D2] f16x2
__global__ __launch_bounds__(256) void etab_kernel(
    const float* __restrict__ ee0, const float* __restrict__ ee1,
    uint* __restrict__ etab)
{
    int i = blockIdx.x * 256 + threadIdx.x;
    const int total = NLAYERS * 18 * D2;
    if (i >= total) return;
    int d2 = i % D2;
    int rest = i / D2;
    int c = rest % 18, l = rest / 18;
    int btv = c / 3, bdv = c % 3;
    const float* r0 = ee0 + ((size_t)l * 6 + btv) * D + d2 * 2;
    const float* r1 = ee1 + ((size_t)l * 3 + bdv) * D + d2 * 2;
    etab[i] = pack2h(r0[0] + r1[0], r0[1] + r1[1]);
}

// ---------------------------------------------------------------- BN fold prep
__global__ void prep_bn_kernel(
    const float* __restrict__ b2, const float* __restrict__ gamma,
    const float* __restrict__ beta, const float* __restrict__ mean,
    const float* __restrict__ var, float* __restrict__ scale2,
    float* __restrict__ shift2, int n)
{
    int i = blockIdx.x * blockDim.x + threadIdx.x;
    if (i >= n) return;
    float s = gamma[i] * rsqrtf(var[i] + BN_EPS);
    scale2[i] = s;
    shift2[i] = (b2[i] - mean[i]) * s + beta[i];
}

// ---------------------------------------------------------------- weight conversion (f32 -> f16, MFMA-tile-linear)
// flat pos = (((nt*KS + ks)*4 + kg)*128 + c)*8 + j ; element W[k=ks*32+kg*8+j][n=nt*128+c]
__global__ __launch_bounds__(256) void conv_w_kernel(
    const float* __restrict__ W1, const float* __restrict__ W2,
    ushort* __restrict__ w1h, ushort* __restrict__ w2h)
{
    int i = blockIdx.x * blockDim.x + threadIdx.x;
    const int PER = P1 + P2;
    if (i >= NLAYERS * PER) return;
    int l = i / PER;
    int r = i - l * PER;
    float v;
    ushort* ph;
    if (r < P1) {
        int pos = r;
        int j = pos & 7, c = (pos >> 3) & 127, kg = (pos >> 10) & 3;
        int rest = pos >> 12;
        int ks = rest % KS1, nt = rest / KS1;
        int k = ks * 32 + kg * 8 + j, n = nt * 128 + c;
        v = (k < D && n < HD) ? W1[(size_t)l * D * HD + (size_t)k * HD + n] : 0.f;
        ph = w1h + (size_t)l * P1 + pos;
    } else {
        int pos = r - P1;
        int j = pos & 7, c = (pos >> 3) & 127, kg = (pos >> 10) & 3;
        int rest = pos >> 12;
        int ks = rest % KS2, nt = rest / KS2;
        int k = ks * 32 + kg * 8 + j, n = nt * 128 + c;
        v = (k < HD && n < D) ? W2[(size_t)l * HD * D + (size_t)k * D + n] : 0.f;
        ph = w2h + (size_t)l * P2 + pos;
    }
    *ph = f2h(v);
}

// ---------------------------------------------------------------- fused layer kernel: aggregate + MLP
// block = 64 node rows, 512 threads (8 waves). LDS 80KB (2 blocks/CU), one
// buffer time-multiplexed: A-tile (swizzled) -> hidden -> output staging.
// Phase 0: CSR gather agg = sum(h[src]+etab) in f32 regs -> ldsA (XOR-swizzled chunks)
// Phase 1: GEMM1 + bias + relu -> ldsH (shfl-paired b32 writes)
// Phase 2: GEMM2 + BN (+relu) -> LDS staging -> coalesced global write
template<bool RELU2>
__global__ __launch_bounds__(512, 4) void fused_mlp_kernel(
    const uint* __restrict__ Hin,      // h_in [N][D2] f16x2
    const uint* __restrict__ etab_l,   // [18][D2]
    const int* __restrict__ esrc, const unsigned char* __restrict__ ecomb,
    const int* __restrict__ offsets,
    const uint4* __restrict__ B1,      // W1 tiled, layer base
    const uint4* __restrict__ B2,      // W2 tiled, layer base
    const float* __restrict__ bias1,   // [600]
    const float* __restrict__ scale2,  // [300]
    const float* __restrict__ shift2,  // [300]
    uint* __restrict__ Hout,           // h_out [N][D2] f16x2
    int M)
{
    __shared__ ushort lds[KS2 * 4 * 64 * 8];    // 80 KB, time-multiplexed

    int t = threadIdx.x;
    int lane = t & 63;
    int wid = t >> 6;                 // 0..7
    int lanelo = lane & 15;
    int kg = lane >> 4;
    int m0 = blockIdx.x * 64;

    // ---- Phase 0: gather-aggregate into ldsA (swizzled chunk = q*64 + (row^(q&7))) ----
    {
        uint* ldsAu = (uint*)lds;
        int rbase = wid * 8;
        for (int rr = 0; rr < 8; ++rr) {
            int rowl = rbase + rr;
            int v = m0 + rowl;
            float ax0 = 0.f, ay0 = 0.f, ax1 = 0.f, ay1 = 0.f, ax2 = 0.f, ay2 = 0.f;
            if (v < M) {
                int p0 = offsets[v], p1 = offsets[v + 1];
                for (int p = p0; p < p1; ++p) {
                    int s = esrc[p];
                    int c = ecomb[p];
                    const uint* hr = Hin + (size_t)s * D2;
                    const uint* er = etab_l + c * D2;
                    int d0 = lane, d1 = lane + 64, dq = lane + 128;
                    uint hv0 = hr[d0], ev0 = er[d0];
                    uint hv1 = hr[d1], ev1 = er[d1];
                    uint hv2 = 0u, ev2 = 0u;
                    if (dq < D2) { hv2 = hr[dq]; ev2 = er[dq]; }
                    ax0 += h2f((ushort)(hv0 & 0xffffu)) + h2f((ushort)(ev0 & 0xffffu));
                    ay0 += h2f((ushort)(hv0 >> 16))     + h2f((ushort)(ev0 >> 16));
                    ax1 += h2f((ushort)(hv1 & 0xffffu)) + h2f((ushort)(ev1 & 0xffffu));
                    ay1 += h2f((ushort)(hv1 >> 16))     + h2f((ushort)(ev1 >> 16));
                    ax2 += h2f((ushort)(hv2 & 0xffffu)) + h2f((ushort)(ev2 & 0xffffu));
                    ay2 += h2f((ushort)(hv2 >> 16))     + h2f((ushort)(ev2 >> 16));
                }
            }
            // store: uint at dword = chunk*4 + (d2&3), chunk = (d2>>2)*64 + (rowl ^ ((d2>>2)&7))
            {
                int d2 = lane;
                int q = d2 >> 2;
                ldsAu[(q * 64 + (rowl ^ (q & 7))) * 4 + (d2 & 3)] = pack2h(ax0, ay0);
                d2 = lane + 64;
                q = d2 >> 2;
                ldsAu[(q * 64 + (rowl ^ (q & 7))) * 4 + (d2 & 3)] = pack2h(ax1, ay1);
                d2 = lane + 128;
                if (d2 < 160) {   // data (<150) or K-pad zeros (150..159)
                    uint val = (d2 < D2) ? pack2h(ax2, ay2) : 0u;
                    q = d2 >> 2;
                    ldsAu[(q * 64 + (rowl ^ (q & 7))) * 4 + (d2 & 3)] = val;
                }
            }
        }
    }
    __syncthreads();

    // ---- Phase 1: GEMM1 (64x640), wave wid covers cols [wid*80, wid*80+80) ----
    {
        f32x4 acc[4][5];
#pragma unroll
        for (int mi = 0; mi < 4; ++mi)
#pragma unroll
            for (int ni = 0; ni < 5; ++ni) {
                f32x4 z = {0.f, 0.f, 0.f, 0.f};
                acc[mi][ni] = z;
            }

        int addrb[5];
#pragma unroll
        for (int ni = 0; ni < 5; ++ni) {
            int col = wid * 80 + ni * 16 + lanelo;
            int nt = col >> 7, c = col & 127;
            addrb[ni] = nt * (KS1 * 512) + kg * 128 + c;
        }

        uint4 bn[5];
#pragma unroll
        for (int ni = 0; ni < 5; ++ni) bn[ni] = B1[addrb[ni]];

        const f16x8* ap = (const f16x8*)lds;
#pragma unroll
        for (int ks = 0; ks < KS1; ++ks) {
            uint4 bc[5];
#pragma unroll
            for (int ni = 0; ni < 5; ++ni) bc[ni] = bn[ni];
            if (ks + 1 < KS1) {
#pragma unroll
                for (int ni = 0; ni < 5; ++ni) bn[ni] = B1[addrb[ni] + (ks + 1) * 512];
            }
            int q1 = ks * 4 + kg;
            int ab = q1 * 64 + (lanelo ^ (q1 & 7));
            f16x8 a0 = ap[ab];
            f16x8 a1 = ap[ab + 16];
            f16x8 a2 = ap[ab + 32];
            f16x8 a3 = ap[ab + 48];
#pragma unroll
            for (int ni = 0; ni < 5; ++ni) {
                f16x8 b = *(const f16x8*)&bc[ni];
                acc[0][ni] = __builtin_amdgcn_mfma_f32_16x16x32_f16(a0, b, acc[0][ni], 0, 0, 0);
                acc[1][ni] = __builtin_amdgcn_mfma_f32_16x16x32_f16(a1, b, acc[1][ni], 0, 0, 0);
                acc[2][ni] = __builtin_amdgcn_mfma_f32_16x16x32_f16(a2, b, acc[2][ni], 0, 0, 0);
                acc[3][ni] = __builtin_amdgcn_mfma_f32_16x16x32_f16(a3, b, acc[3][ni], 0, 0, 0);
            }
        }

        // all waves done READING ldsA before overwriting with hidden
        __syncthreads();

        // epilogue: +bias, relu; pack adjacent-col pairs via shfl -> b32 LDS writes
        uint* ldsHu = (uint*)lds;
#pragma unroll
        for (int ni = 0; ni < 5; ++ni) {
            int col = wid * 80 + ni * 16 + lanelo;
            float bias = (col < HD) ? bias1[col] : 0.f;
            int ks2 = col >> 5, g2 = (col >> 3) & 3, j2 = col & 7;
            int dbase = (ks2 * 4 + g2) * 256 + (j2 >> 1);
#pragma unroll
            for (int mi = 0; mi < 4; ++mi) {
                int r0 = mi * 16 + kg * 4;
#pragma unroll
                for (int r = 0; r < 4; ++r) {
                    float y = fmaxf(acc[mi][ni][r] + bias, 0.f);
                    float yn = __shfl_xor(y, 1);
                    if ((lanelo & 1) == 0)
                        ldsHu[dbase + (r0 + r) * 4] = pack2h(y, yn);
                }
            }
        }
    }
    __syncthreads();

    // ---- Phase 2: GEMM2 (64x384), wave wid covers cols [wid*48, wid*48+48) ----
    {
        f32x4 acc[4][3];
#pragma unroll
        for (int mi = 0; mi < 4; ++mi)
#pragma unroll
            for (int ni = 0; ni < 3; ++ni) {
                f32x4 z = {0.f, 0.f, 0.f, 0.f};
                acc[mi][ni] = z;
            }

        int addrb[3];
#pragma unroll
        for (int ni = 0; ni < 3; ++ni) {
            int col = wid * 48 + ni * 16 + lanelo;
            int nt = col >> 7, c = col & 127;
            addrb[ni] = nt * (KS2 * 512) + kg * 128 + c;
        }

        uint4 bn[3];
#pragma unroll
        for (int ni = 0; ni < 3; ++ni) bn[ni] = B2[addrb[ni]];

        const f16x8* hp = (const f16x8*)lds;
#pragma unroll
        for (int ks = 0; ks < KS2; ++ks) {
            uint4 bc[3];
#pragma unroll
            for (int ni = 0; ni < 3; ++ni) bc[ni] = bn[ni];
            if (ks + 1 < KS2) {
#pragma unroll
                for (int ni = 0; ni < 3; ++ni) bn[ni] = B2[addrb[ni] + (ks + 1) * 512];
            }
            int ab = (ks * 4 + kg) * 64 + lanelo;
            f16x8 a0 = hp[ab];
            f16x8 a1 = hp[ab + 16];
            f16x8 a2 = hp[ab + 32];
            f16x8 a3 = hp[ab + 48];
#pragma unroll
            for (int ni = 0; ni < 3; ++ni) {
                f16x8 b = *(const f16x8*)&bc[ni];
                acc[0][ni] = __builtin_amdgcn_mfma_f32_16x16x32_f16(a0, b, acc[0][ni], 0, 0, 0);
                acc[1][ni] = __builtin_amdgcn_mfma_f32_16x16x32_f16(a1, b, acc[1][ni], 0, 0, 0);
                acc[2][ni] = __builtin_amdgcn_mfma_f32_16x16x32_f16(a2, b, acc[2][ni], 0, 0, 0);
                acc[3][ni] = __builtin_amdgcn_mfma_f32_16x16x32_f16(a3, b, acc[3][ni], 0, 0, 0);
            }
        }

        // all waves done READING ldsH before overwriting with output staging
        __syncthreads();

        // epilogue: BN (+relu); pack pairs -> LDS staging [64][154] uints
        uint* stg = (uint*)lds;
#pragma unroll
        for (int ni = 0; ni < 3; ++ni) {
            int col = wid * 48 + ni * 16 + lanelo;
            float sc = 1.f, sh = 0.f;
            if (col < D) { sc = scale2[col]; sh = shift2[col]; }
#pragma unroll
            for (int mi = 0; mi < 4; ++mi) {
                int r0 = mi * 16 + kg * 4;
#pragma unroll
                for (int r = 0; r < 4; ++r) {
                    float y = acc[mi][ni][r] * sc + sh;
                    if (RELU2) y = fmaxf(y, 0.f);
                    float yn = __shfl_xor(y, 1);
                    if ((lanelo & 1) == 0 && col < D)
                        stg[(r0 + r) * 154 + (col >> 1)] = pack2h(y, yn);
                }
            }
        }
    }
    __syncthreads();

    // ---- coalesced cooperative write: 64 rows x 150 uints ----
    {
        const uint* stg = (const uint*)lds;
#pragma unroll
        for (int i = 0; i < 19; ++i) {
            int g = t + i * 512;
            if (g < 64 * 150) {
                int row = g / 150, c = g - row * 150;
                if (m0 + row < M)
                    Hout[(size_t)(m0 + row) * D2 + c] = stg[row * 154 + c];
            }
        }
    }
}

// ---------------------------------------------------------------- avg pool
__global__ __launch_bounds__(320) void pool_kernel(
    const ushort* __restrict__ h, const int* __restrict__ gid,
    float* __restrict__ gavg, int N)
{
    int g = blockIdx.x;
    int lo = 0, hi = N;
    while (lo < hi) { int mid = (lo + hi) >> 1; if (gid[mid] < g) lo = mid + 1; else hi = mid; }
    int start = lo;
    lo = start; hi = N;
    while (lo < hi) { int mid = (lo + hi) >> 1; if (gid[mid] <= g) lo = mid + 1; else hi = mid; }
    int end = lo;
    int d = threadIdx.x;
    if (d >= D) return;
    float s = 0.f;
    for (int i = start; i < end; ++i) s += h2f(h[(size_t)i * D + d]);
    float cnt = (float)(end - start);
    gavg[(size_t)g * D + d] = s / fmaxf(cnt, 1.f);
}

// ---------------------------------------------------------------- head
__global__ __launch_bounds__(256) void head_kernel(
    const float* __restrict__ gavg, const float* __restrict__ Wd,
    const float* __restrict__ bd, float* __restrict__ out)
{
    int g = blockIdx.x;
    int j = threadIdx.x;
    float s = bd[j];
    const float* gr = gavg + (size_t)g * D;
    for (int d = 0; d < D; ++d) s = fmaf(gr[d], Wd[(size_t)d * 256 + j], s);
    out[(size_t)g * 256 + j] = s;
}

// ================================================================ launch
extern "C" void kernel_launch(void* const* d_in, const int* in_sizes, int n_in,
                              void* d_out, int out_size, void* d_ws, size_t ws_size,
                              hipStream_t stream)
{
    const int*   atomic_number = (const int*)d_in[0];
    const int*   chirality     = (const int*)d_in[1];
    const int*   bond_type     = (const int*)d_in[2];
    const int*   bond_dir      = (const int*)d_in[3];
    const int*   src           = (const int*)d_in[4];
    const int*   dst           = (const int*)d_in[5];
    const int*   graph_ids     = (const int*)d_in[6];
    const float* node_emb0     = (const float*)d_in[8];
    const float* node_emb1     = (const float*)d_in[9];
    const float* edge_emb0     = (const float*)d_in[10];
    const float* edge_emb1     = (const float*)d_in[11];
    const float* W1            = (const float*)d_in[12];
    const float* b1            = (const float*)d_in[13];
    const float* W2            = (const float*)d_in[14];
    const float* b2            = (const float*)d_in[15];
    const float* bn_gamma      = (const float*)d_in[16];
    const float* bn_beta       = (const float*)d_in[17];
    const float* bn_mean       = (const float*)d_in[18];
    const float* bn_var        = (const float*)d_in[19];
    const float* Wd            = (const float*)d_in[20];
    const float* bd            = (const float*)d_in[21];

    int N = in_sizes[0];
    int E = in_sizes[2];
    int G = out_size / 256;
    float* out = (float*)d_out;

    // ---- ws layout (ping-pong h; no agg buffer) ----
    char* ws = (char*)d_ws;
    size_t offs = 0;
    auto take = [&](size_t nbytes) -> char* {
        char* p = ws + offs;
        offs += (nbytes + 255) & ~(size_t)255;
        return p;
    };
    ushort* w1h    = (ushort*)take((size_t)NLAYERS * P1 * 2);
    ushort* w2h    = (ushort*)take((size_t)NLAYERS * P2 * 2);
    uint*   h0     = (uint*)take((size_t)N * D2 * 4);
    uint*   h1     = (uint*)take((size_t)N * D2 * 4);
    int*    deg    = (int*)take((size_t)N * 4);
    int*    offsets= (int*)take((size_t)(N + 1) * 4);
    int*    cursor = (int*)take((size_t)N * 4);
    int*    csr    = (int*)take((size_t)E * 4);
    int*    esrc   = (int*)take((size_t)E * 4);
    unsigned char* ecomb = (unsigned char*)take((size_t)E);
    uint*   etab   = (uint*)take((size_t)NLAYERS * 18 * D2 * 4);
    int*    part   = (int*)take((size_t)256 * 4);
    float*  gavg   = (float*)take((size_t)G * D * 4);
    float*  scale2 = (float*)take((size_t)NLAYERS * D * 4);
    float*  shift2 = (float*)take((size_t)NLAYERS * D * 4);

    // ---- tiny prep ----
    prep_bn_kernel<<<(NLAYERS * D + 255) / 256, 256, 0, stream>>>(
        b2, bn_gamma, bn_beta, bn_mean, bn_var, scale2, shift2, NLAYERS * D);
    {
        int T = NLAYERS * (P1 + P2);
        conv_w_kernel<<<(T + 255) / 256, 256, 0, stream>>>(W1, W2, w1h, w2h);
    }
    etab_kernel<<<(NLAYERS * 18 * D2 + 255) / 256, 256, 0, stream>>>(
        edge_emb0, edge_emb1, etab);
    embed_kernel<<<(N + 3) / 4, 256, 0, stream>>>(
        atomic_number, chirality, node_emb0, node_emb1, h0, N);

    // ---- CSR build (once; layer-invariant) ----
    int NB = (N + SCAN_BLK - 1) / SCAN_BLK;
    zero_kernel<<<(int)(((size_t)N + 1023) / 1024), 256, 0, stream>>>((uint4*)deg, (long)N / 4);
    count_kernel<<<(E + 255) / 256, 256, 0, stream>>>(dst, deg, E);
    scan_part_kernel<<<NB, 256, 0, stream>>>(deg, part, N);
    scan_top_kernel<<<1, 256, 0, stream>>>(part, NB);
    scan_write_kernel<<<NB, 256, 0, stream>>>(deg, part, offsets, cursor, N, E);
    scatter_kernel<<<(E + 255) / 256, 256, 0, stream>>>(dst, cursor, csr, E);
    eprep_kernel<<<(E + 255) / 256, 256, 0, stream>>>(csr, src, bond_type, bond_dir, esrc, ecomb, E);

    int mlp_grid = (N + 63) / 64;
    for (int l = 0; l < NLAYERS; ++l) {
        const uint* hin = (l & 1) ? h1 : h0;
        uint* hout      = (l & 1) ? h0 : h1;
        if (l < NLAYERS - 1)
            fused_mlp_kernel<true><<<mlp_grid, 512, 0, stream>>>(
                hin, etab + (size_t)l * 18 * D2, esrc, ecomb, offsets,
                (const uint4*)(w1h + (size_t)l * P1),
                (const uint4*)(w2h + (size_t)l * P2),
                b1 + (size_t)l * HD,
                scale2 + (size_t)l * D, shift2 + (size_t)l * D,
                hout, N);
        else
            fused_mlp_kernel<false><<<mlp_grid, 512, 0, stream>>>(
                hin, etab + (size_t)l * 18 * D2, esrc, ecomb, offsets,
                (const uint4*)(w1h + (size_t)l * P1),
                (const uint4*)(w2h + (size_t)l * P2),
                b1 + (size_t)l * HD,
                scale2 + (size_t)l * D, shift2 + (size_t)l * D,
                hout, N);
    }

    // final h is h1 (odd number of layers -> last write went to h1)
    pool_kernel<<<G, 320, 0, stream>>>((const ushort*)h1, graph_ids, gavg, N);
    head_kernel<<<G, 256, 0, stream>>>(gavg, Wd, bd, out);
}

// Round 10
// 1680.200 us; speedup vs baseline: 11.6759x; 1.0955x over previous
//
#include <hip/hip_runtime.h>
#include <hip/hip_bf16.h>
#include <hip/hip_fp16.h>

#define D 300
#define D2 150          // f16 pairs per row
#define HD 600
#define NLAYERS 5
#define BN_EPS 1e-5f

// GEMM1: K=300->320 (KS1=10), N=600->640. GEMM2: K=600->640 (KS2=20), N=300->384.
#define KS1 10
#define NT1 5
#define KS2 20
#define NT2 3
#define P1 (NT1*KS1*4096)   // 204800 f16 per layer (w1 tiled)
#define P2 (NT2*KS2*4096)   // 245760 f16 per layer (w2 tiled)

#define SCAN_BLK 1024

typedef _Float16 f16x8 __attribute__((ext_vector_type(8)));
typedef __attribute__((ext_vector_type(4))) float f32x4;

// ---------------------------------------------------------------- f16 helpers
__device__ inline ushort f2h(float x) {
    __half h = __float2half(x);
    return *reinterpret_cast<ushort*>(&h);
}
__device__ inline float h2f(ushort u) {
    __half h;
    *reinterpret_cast<ushort*>(&h) = u;
    return __half2float(h);
}
__device__ inline uint pack2h(float lo, float hi) {
    return (uint)f2h(lo) | ((uint)f2h(hi) << 16);
}

// ---------------------------------------------------------------- zero fill
__global__ __launch_bounds__(256) void zero_kernel(uint4* __restrict__ p, long n4)
{
    long i = (long)blockIdx.x * blockDim.x + threadIdx.x;
    long stride = (long)gridDim.x * blockDim.x;
    uint4 z = make_uint4(0u, 0u, 0u, 0u);
    for (; i < n4; i += stride) p[i] = z;
}

// ---------------------------------------------------------------- embed (h f16)
__global__ __launch_bounds__(256) void embed_kernel(
    const int* __restrict__ an, const int* __restrict__ ch,
    const float* __restrict__ e0, const float* __restrict__ e1,
    uint* __restrict__ h_u, int N)
{
    int node = blockIdx.x * 4 + (threadIdx.x >> 6);
    if (node >= N) return;
    int lane = threadIdx.x & 63;
    const float* r0 = e0 + (size_t)an[node] * D;
    const float* r1 = e1 + (size_t)ch[node] * D;
    uint* hr = h_u + (size_t)node * D2;
    for (int d2 = lane; d2 < D2; d2 += 64) {
        float2 a = *(const float2*)(r0 + d2 * 2);
        float2 b = *(const float2*)(r1 + d2 * 2);
        hr[d2] = pack2h(a.x + b.x, a.y + b.y);
    }
}

// ---------------------------------------------------------------- CSR build (once)
__global__ __launch_bounds__(256) void count_kernel(
    const int* __restrict__ dst, int* __restrict__ deg, int E)
{
    int e = blockIdx.x * 256 + threadIdx.x;
    if (e < E) atomicAdd(&deg[dst[e]], 1);
}

__global__ __launch_bounds__(256) void scan_part_kernel(
    const int* __restrict__ deg, int* __restrict__ part, int N)
{
    __shared__ int sm[256];
    int b = blockIdx.x, t = threadIdx.x;
    int base = b * SCAN_BLK + t * 4;
    int s = 0;
#pragma unroll
    for (int j = 0; j < 4; ++j) { int i = base + j; if (i < N) s += deg[i]; }
    sm[t] = s;
    __syncthreads();
    for (int off = 128; off > 0; off >>= 1) {
        if (t < off) sm[t] += sm[t + off];
        __syncthreads();
    }
    if (t == 0) part[b] = sm[0];
}

__global__ __launch_bounds__(256) void scan_top_kernel(int* __restrict__ part, int NB)
{
    __shared__ int sm[256];
    int t = threadIdx.x;
    int own = (t < NB) ? part[t] : 0;
    sm[t] = own;
    __syncthreads();
    for (int off = 1; off < 256; off <<= 1) {
        int u = (t >= off) ? sm[t - off] : 0;
        __syncthreads();
        sm[t] += u;
        __syncthreads();
    }
    if (t < NB) part[t] = sm[t] - own;   // exclusive
}

__global__ __launch_bounds__(256) void scan_write_kernel(
    const int* __restrict__ deg, const int* __restrict__ part,
    int* __restrict__ offsets, int* __restrict__ cursor, int N, int E)
{
    __shared__ int sm[256];
    int b = blockIdx.x, t = threadIdx.x;
    int base = b * SCAN_BLK + t * 4;
    int v[4], s = 0;
#pragma unroll
    for (int j = 0; j < 4; ++j) { int i = base + j; v[j] = (i < N) ? deg[i] : 0; s += v[j]; }
    int own = s;
    sm[t] = s;
    __syncthreads();
    for (int off = 1; off < 256; off <<= 1) {
        int u = (t >= off) ? sm[t - off] : 0;
        __syncthreads();
        sm[t] += u;
        __syncthreads();
    }
    int ex = sm[t] - own + part[b];
#pragma unroll
    for (int j = 0; j < 4; ++j) {
        int i = base + j;
        if (i < N) { offsets[i] = ex; cursor[i] = ex; ex += v[j]; }
    }
    if (b == 0 && t == 0) offsets[N] = E;
}

__global__ __launch_bounds__(256) void scatter_kernel(
    const int* __restrict__ dst, int* __restrict__ cursor,
    int* __restrict__ csr, int E)
{
    int e = blockIdx.x * 256 + threadIdx.x;
    if (e < E) {
        int pos = atomicAdd(&cursor[dst[e]], 1);
        csr[pos] = e;
    }
}

// ---------------------------------------------------------------- edge prep (once): CSR-ordered src + combo id
__global__ __launch_bounds__(256) void eprep_kernel(
    const int* __restrict__ csr, const int* __restrict__ src,
    const int* __restrict__ bt, const int* __restrict__ bd,
    int* __restrict__ esrc, unsigned char* __restrict__ ecomb, int E)
{
    int p = blockIdx.x * 256 + threadIdx.x;
    if (p < E) {
        int e = csr[p];
        esrc[p] = src[e];
        ecomb[p] = (unsigned char)(bt[e] * 3 + bd[e]);
    }
}

// ---------------------------------------------------------------- edge-emb combo table: etab[l][c=bt*3+bd][D2] f16x2
__global__ __launch_bounds__(256) void etab_kernel(
    const float* __restrict__ ee0, const float* __restrict__ ee1,
    uint* __restrict__ etab)
{
    int i = blockIdx.x * 256 + threadIdx.x;
    const int total = NLAYERS * 18 * D2;
    if (i >= total) return;
    int d2 = i % D2;
    int rest = i / D2;
    int c = rest % 18, l = rest / 18;
    int btv = c / 3, bdv = c % 3;
    const float* r0 = ee0 + ((size_t)l * 6 + btv) * D + d2 * 2;
    const float* r1 = ee1 + ((size_t)l * 3 + bdv) * D + d2 * 2;
    etab[i] = pack2h(r0[0] + r1[0], r0[1] + r1[1]);
}

// ---------------------------------------------------------------- BN fold prep
__global__ void prep_bn_kernel(
    const float* __restrict__ b2, const float* __restrict__ gamma,
    const float* __restrict__ beta, const float* __restrict__ mean,
    const float* __restrict__ var, float* __restrict__ scale2,
    float* __restrict__ shift2, int n)
{
    int i = blockIdx.x * blockDim.x + threadIdx.x;
    if (i >= n) return;
    float s = gamma[i] * rsqrtf(var[i] + BN_EPS);
    scale2[i] = s;
    shift2[i] = (b2[i] - mean[i]) * s + beta[i];
}

// ---------------------------------------------------------------- weight conversion (f32 -> f16, MFMA-tile-linear)
// flat pos = (((nt*KS + ks)*4 + kg)*128 + c)*8 + j ; element W[k=ks*32+kg*8+j][n=nt*128+c]
__global__ __launch_bounds__(256) void conv_w_kernel(
    const float* __restrict__ W1, const float* __restrict__ W2,
    ushort* __restrict__ w1h, ushort* __restrict__ w2h)
{
    int i = blockIdx.x * blockDim.x + threadIdx.x;
    const int PER = P1 + P2;
    if (i >= NLAYERS * PER) return;
    int l = i / PER;
    int r = i - l * PER;
    float v;
    ushort* ph;
    if (r < P1) {
        int pos = r;
        int j = pos & 7, c = (pos >> 3) & 127, kg = (pos >> 10) & 3;
        int rest = pos >> 12;
        int ks = rest % KS1, nt = rest / KS1;
        int k = ks * 32 + kg * 8 + j, n = nt * 128 + c;
        v = (k < D && n < HD) ? W1[(size_t)l * D * HD + (size_t)k * HD + n] : 0.f;
        ph = w1h + (size_t)l * P1 + pos;
    } else {
        int pos = r - P1;
        int j = pos & 7, c = (pos >> 3) & 127, kg = (pos >> 10) & 3;
        int rest = pos >> 12;
        int ks = rest % KS2, nt = rest / KS2;
        int k = ks * 32 + kg * 8 + j, n = nt * 128 + c;
        v = (k < HD && n < D) ? W2[(size_t)l * HD * D + (size_t)k * D + n] : 0.f;
        ph = w2h + (size_t)l * P2 + pos;
    }
    *ph = f2h(v);
}

// ---------------------------------------------------------------- fused layer kernel: aggregate + MLP
// block = 64 node rows, 512 threads (8 waves). LDS 80KB (2 blocks/CU), one
// buffer time-multiplexed: A-tile (swizzled) -> hidden -> output staging.
// Phase 0: quarter-wave-per-row CSR gather (4 rows in flight per wave, 2 passes)
// Phase 1: GEMM1 + bias + relu -> ldsH (shfl-paired b32 writes)
// Phase 2: GEMM2 (2-deep B prefetch) + BN (+relu) -> LDS staging -> coalesced write
template<bool RELU2>
__global__ __launch_bounds__(512, 4) void fused_mlp_kernel(
    const uint* __restrict__ Hin,      // h_in [N][D2] f16x2
    const uint* __restrict__ etab_l,   // [18][D2]
    const int* __restrict__ esrc, const unsigned char* __restrict__ ecomb,
    const int* __restrict__ offsets,
    const uint4* __restrict__ B1,      // W1 tiled, layer base
    const uint4* __restrict__ B2,      // W2 tiled, layer base
    const float* __restrict__ bias1,   // [600]
    const float* __restrict__ scale2,  // [300]
    const float* __restrict__ shift2,  // [300]
    uint* __restrict__ Hout,           // h_out [N][D2] f16x2
    int M)
{
    __shared__ ushort lds[KS2 * 4 * 64 * 8];    // 80 KB, time-multiplexed

    int t = threadIdx.x;
    int lane = t & 63;
    int wid = t >> 6;                 // 0..7
    int lanelo = lane & 15;
    int kg = lane >> 4;
    int m0 = blockIdx.x * 64;

    // ---- Phase 0: gather-aggregate, quarter-wave per row (4 rows/wave in flight) ----
    // lane q = lane>>4 owns row wid*8 + pass*4 + q; ql = lane&15 covers d2 = ql + j*16,
    // j<10 -> exactly [0,160): data (<150) + zero K-pad (150..159).
    {
        uint* ldsAu = (uint*)lds;
        int q = lane >> 4;
        int ql = lane & 15;
#pragma unroll
        for (int pass = 0; pass < 2; ++pass) {
            int rowl = wid * 8 + pass * 4 + q;
            int v = m0 + rowl;
            float ax[10], ay[10];
#pragma unroll
            for (int j = 0; j < 10; ++j) { ax[j] = 0.f; ay[j] = 0.f; }
            if (v < M) {
                int p0 = offsets[v], p1 = offsets[v + 1];
                for (int p = p0; p < p1; ++p) {
                    int s = esrc[p];
                    int c = ecomb[p];
                    const uint* hr = Hin + (size_t)s * D2;
                    const uint* er = etab_l + c * D2;
#pragma unroll
                    for (int j = 0; j < 10; ++j) {
                        int d2 = ql + j * 16;
                        if (d2 < D2) {
                            uint hv = hr[d2];
                            uint ev = er[d2];
                            ax[j] += h2f((ushort)(hv & 0xffffu)) + h2f((ushort)(ev & 0xffffu));
                            ay[j] += h2f((ushort)(hv >> 16))     + h2f((ushort)(ev >> 16));
                        }
                    }
                }
            }
            // swizzled store: chunk = (d2>>2)*64 + (rowl ^ ((d2>>2)&7)); zeros for pad/overrun rows
#pragma unroll
            for (int j = 0; j < 10; ++j) {
                int d2 = ql + j * 16;
                int qc = d2 >> 2;
                ldsAu[(qc * 64 + (rowl ^ (qc & 7))) * 4 + (d2 & 3)] = pack2h(ax[j], ay[j]);
            }
        }
    }
    __syncthreads();

    // ---- Phase 1: GEMM1 (64x640), wave wid covers cols [wid*80, wid*80+80) ----
    {
        f32x4 acc[4][5];
#pragma unroll
        for (int mi = 0; mi < 4; ++mi)
#pragma unroll
            for (int ni = 0; ni < 5; ++ni) {
                f32x4 z = {0.f, 0.f, 0.f, 0.f};
                acc[mi][ni] = z;
            }

        int addrb[5];
#pragma unroll
        for (int ni = 0; ni < 5; ++ni) {
            int col = wid * 80 + ni * 16 + lanelo;
            int nt = col >> 7, c = col & 127;
            addrb[ni] = nt * (KS1 * 512) + kg * 128 + c;
        }

        uint4 bn[5];
#pragma unroll
        for (int ni = 0; ni < 5; ++ni) bn[ni] = B1[addrb[ni]];

        const f16x8* ap = (const f16x8*)lds;
#pragma unroll
        for (int ks = 0; ks < KS1; ++ks) {
            uint4 bc[5];
#pragma unroll
            for (int ni = 0; ni < 5; ++ni) bc[ni] = bn[ni];
            if (ks + 1 < KS1) {
#pragma unroll
                for (int ni = 0; ni < 5; ++ni) bn[ni] = B1[addrb[ni] + (ks + 1) * 512];
            }
            int q1 = ks * 4 + kg;
            int ab = q1 * 64 + (lanelo ^ (q1 & 7));
            f16x8 a0 = ap[ab];
            f16x8 a1 = ap[ab + 16];
            f16x8 a2 = ap[ab + 32];
            f16x8 a3 = ap[ab + 48];
#pragma unroll
            for (int ni = 0; ni < 5; ++ni) {
                f16x8 b = *(const f16x8*)&bc[ni];
                acc[0][ni] = __builtin_amdgcn_mfma_f32_16x16x32_f16(a0, b, acc[0][ni], 0, 0, 0);
                acc[1][ni] = __builtin_amdgcn_mfma_f32_16x16x32_f16(a1, b, acc[1][ni], 0, 0, 0);
                acc[2][ni] = __builtin_amdgcn_mfma_f32_16x16x32_f16(a2, b, acc[2][ni], 0, 0, 0);
                acc[3][ni] = __builtin_amdgcn_mfma_f32_16x16x32_f16(a3, b, acc[3][ni], 0, 0, 0);
            }
        }

        // all waves done READING ldsA before overwriting with hidden
        __syncthreads();

        // epilogue: +bias, relu; pack adjacent-col pairs via shfl -> b32 LDS writes
        uint* ldsHu = (uint*)lds;
#pragma unroll
        for (int ni = 0; ni < 5; ++ni) {
            int col = wid * 80 + ni * 16 + lanelo;
            float bias = (col < HD) ? bias1[col] : 0.f;
            int ks2 = col >> 5, g2 = (col >> 3) & 3, j2 = col & 7;
            int dbase = (ks2 * 4 + g2) * 256 + (j2 >> 1);
#pragma unroll
            for (int mi = 0; mi < 4; ++mi) {
                int r0 = mi * 16 + kg * 4;
#pragma unroll
                for (int r = 0; r < 4; ++r) {
                    float y = fmaxf(acc[mi][ni][r] + bias, 0.f);
                    float yn = __shfl_xor(y, 1);
                    if ((lanelo & 1) == 0)
                        ldsHu[dbase + (r0 + r) * 4] = pack2h(y, yn);
                }
            }
        }
    }
    __syncthreads();

    // ---- Phase 2: GEMM2 (64x384), 2-deep B prefetch, wave wid covers 48 cols ----
    {
        f32x4 acc[4][3];
#pragma unroll
        for (int mi = 0; mi < 4; ++mi)
#pragma unroll
            for (int ni = 0; ni < 3; ++ni) {
                f32x4 z = {0.f, 0.f, 0.f, 0.f};
                acc[mi][ni] = z;
            }

        int addrb[3];
#pragma unroll
        for (int ni = 0; ni < 3; ++ni) {
            int col = wid * 48 + ni * 16 + lanelo;
            int nt = col >> 7, c = col & 127;
            addrb[ni] = nt * (KS2 * 512) + kg * 128 + c;
        }

        uint4 bn0[3], bn1[3];
#pragma unroll
        for (int ni = 0; ni < 3; ++ni) bn0[ni] = B2[addrb[ni]];
#pragma unroll
        for (int ni = 0; ni < 3; ++ni) bn1[ni] = B2[addrb[ni] + 512];

        const f16x8* hp = (const f16x8*)lds;
#pragma unroll
        for (int ks = 0; ks < KS2; ++ks) {
            uint4 bc[3];
#pragma unroll
            for (int ni = 0; ni < 3; ++ni) bc[ni] = bn0[ni];
#pragma unroll
            for (int ni = 0; ni < 3; ++ni) bn0[ni] = bn1[ni];
            {
                int nk = (ks + 2 < KS2) ? ks + 2 : KS2 - 1;   // clamped, branchless
#pragma unroll
                for (int ni = 0; ni < 3; ++ni) bn1[ni] = B2[addrb[ni] + nk * 512];
            }
            int ab = (ks * 4 + kg) * 64 + lanelo;
            f16x8 a0 = hp[ab];
            f16x8 a1 = hp[ab + 16];
            f16x8 a2 = hp[ab + 32];
            f16x8 a3 = hp[ab + 48];
#pragma unroll
            for (int ni = 0; ni < 3; ++ni) {
                f16x8 b = *(const f16x8*)&bc[ni];
                acc[0][ni] = __builtin_amdgcn_mfma_f32_16x16x32_f16(a0, b, acc[0][ni], 0, 0, 0);
                acc[1][ni] = __builtin_amdgcn_mfma_f32_16x16x32_f16(a1, b, acc[1][ni], 0, 0, 0);
                acc[2][ni] = __builtin_amdgcn_mfma_f32_16x16x32_f16(a2, b, acc[2][ni], 0, 0, 0);
                acc[3][ni] = __builtin_amdgcn_mfma_f32_16x16x32_f16(a3, b, acc[3][ni], 0, 0, 0);
            }
        }

        // all waves done READING ldsH before overwriting with output staging
        __syncthreads();

        // epilogue: BN (+relu); pack pairs -> LDS staging [64][154] uints
        uint* stg = (uint*)lds;
#pragma unroll
        for (int ni = 0; ni < 3; ++ni) {
            int col = wid * 48 + ni * 16 + lanelo;
            float sc = 1.f, sh = 0.f;
            if (col < D) { sc = scale2[col]; sh = shift2[col]; }
#pragma unroll
            for (int mi = 0; mi < 4; ++mi) {
                int r0 = mi * 16 + kg * 4;
#pragma unroll
                for (int r = 0; r < 4; ++r) {
                    float y = acc[mi][ni][r] * sc + sh;
                    if (RELU2) y = fmaxf(y, 0.f);
                    float yn = __shfl_xor(y, 1);
                    if ((lanelo & 1) == 0 && col < D)
                        stg[(r0 + r) * 154 + (col >> 1)] = pack2h(y, yn);
                }
            }
        }
    }
    __syncthreads();

    // ---- coalesced cooperative write: 64 rows x 150 uints ----
    {
        const uint* stg = (const uint*)lds;
#pragma unroll
        for (int i = 0; i < 19; ++i) {
            int g = t + i * 512;
            if (g < 64 * 150) {
                int row = g / 150, c = g - row * 150;
                if (m0 + row < M)
                    Hout[(size_t)(m0 + row) * D2 + c] = stg[row * 154 + c];
            }
        }
    }
}

// ---------------------------------------------------------------- avg pool
__global__ __launch_bounds__(320) void pool_kernel(
    const ushort* __restrict__ h, const int* __restrict__ gid,
    float* __restrict__ gavg, int N)
{
    int g = blockIdx.x;
    int lo = 0, hi = N;
    while (lo < hi) { int mid = (lo + hi) >> 1; if (gid[mid] < g) lo = mid + 1; else hi = mid; }
    int start = lo;
    lo = start; hi = N;
    while (lo < hi) { int mid = (lo + hi) >> 1; if (gid[mid] <= g) lo = mid + 1; else hi = mid; }
    int end = lo;
    int d = threadIdx.x;
    if (d >= D) return;
    float s = 0.f;
    for (int i = start; i < end; ++i) s += h2f(h[(size_t)i * D + d]);
    float cnt = (float)(end - start);
    gavg[(size_t)g * D + d] = s / fmaxf(cnt, 1.f);
}

// ---------------------------------------------------------------- head
__global__ __launch_bounds__(256) void head_kernel(
    const float* __restrict__ gavg, const float* __restrict__ Wd,
    const float* __restrict__ bd, float* __restrict__ out)
{
    int g = blockIdx.x;
    int j = threadIdx.x;
    float s = bd[j];
    const float* gr = gavg + (size_t)g * D;
    for (int d = 0; d < D; ++d) s = fmaf(gr[d], Wd[(size_t)d * 256 + j], s);
    out[(size_t)g * 256 + j] = s;
}

// ================================================================ launch
extern "C" void kernel_launch(void* const* d_in, const int* in_sizes, int n_in,
                              void* d_out, int out_size, void* d_ws, size_t ws_size,
                              hipStream_t stream)
{
    const int*   atomic_number = (const int*)d_in[0];
    const int*   chirality     = (const int*)d_in[1];
    const int*   bond_type     = (const int*)d_in[2];
    const int*   bond_dir      = (const int*)d_in[3];
    const int*   src           = (const int*)d_in[4];
    const int*   dst           = (const int*)d_in[5];
    const int*   graph_ids     = (const int*)d_in[6];
    const float* node_emb0     = (const float*)d_in[8];
    const float* node_emb1     = (const float*)d_in[9];
    const float* edge_emb0     = (const float*)d_in[10];
    const float* edge_emb1     = (const float*)d_in[11];
    const float* W1            = (const float*)d_in[12];
    const float* b1            = (const float*)d_in[13];
    const float* W2            = (const float*)d_in[14];
    const float* b2            = (const float*)d_in[15];
    const float* bn_gamma      = (const float*)d_in[16];
    const float* bn_beta       = (const float*)d_in[17];
    const float* bn_mean       = (const float*)d_in[18];
    const float* bn_var        = (const float*)d_in[19];
    const float* Wd            = (const float*)d_in[20];
    const float* bd            = (const float*)d_in[21];

    int N = in_sizes[0];
    int E = in_sizes[2];
    int G = out_size / 256;
    float* out = (float*)d_out;

    // ---- ws layout (ping-pong h; no agg buffer) ----
    char* ws = (char*)d_ws;
    size_t offs = 0;
    auto take = [&](size_t nbytes) -> char* {
        char* p = ws + offs;
        offs += (nbytes + 255) & ~(size_t)255;
        return p;
    };
    ushort* w1h    = (ushort*)take((size_t)NLAYERS * P1 * 2);
    ushort* w2h    = (ushort*)take((size_t)NLAYERS * P2 * 2);
    uint*   h0     = (uint*)take((size_t)N * D2 * 4);
    uint*   h1     = (uint*)take((size_t)N * D2 * 4);
    int*    deg    = (int*)take((size_t)N * 4);
    int*    offsets= (int*)take((size_t)(N + 1) * 4);
    int*    cursor = (int*)take((size_t)N * 4);
    int*    csr    = (int*)take((size_t)E * 4);
    int*    esrc   = (int*)take((size_t)E * 4);
    unsigned char* ecomb = (unsigned char*)take((size_t)E);
    uint*   etab   = (uint*)take((size_t)NLAYERS * 18 * D2 * 4);
    int*    part   = (int*)take((size_t)256 * 4);
    float*  gavg   = (float*)take((size_t)G * D * 4);
    float*  scale2 = (float*)take((size_t)NLAYERS * D * 4);
    float*  shift2 = (float*)take((size_t)NLAYERS * D * 4);

    // ---- tiny prep ----
    prep_bn_kernel<<<(NLAYERS * D + 255) / 256, 256, 0, stream>>>(
        b2, bn_gamma, bn_beta, bn_mean, bn_var, scale2, shift2, NLAYERS * D);
    {
        int T = NLAYERS * (P1 + P2);
        conv_w_kernel<<<(T + 255) / 256, 256, 0, stream>>>(W1, W2, w1h, w2h);
    }
    etab_kernel<<<(NLAYERS * 18 * D2 + 255) / 256, 256, 0, stream>>>(
        edge_emb0, edge_emb1, etab);
    embed_kernel<<<(N + 3) / 4, 256, 0, stream>>>(
        atomic_number, chirality, node_emb0, node_emb1, h0, N);

    // ---- CSR build (once; layer-invariant) ----
    int NB = (N + SCAN_BLK - 1) / SCAN_BLK;
    zero_kernel<<<(int)(((size_t)N + 1023) / 1024), 256, 0, stream>>>((uint4*)deg, (long)N / 4);
    count_kernel<<<(E + 255) / 256, 256, 0, stream>>>(dst, deg, E);
    scan_part_kernel<<<NB, 256, 0, stream>>>(deg, part, N);
    scan_top_kernel<<<1, 256, 0, stream>>>(part, NB);
    scan_write_kernel<<<NB, 256, 0, stream>>>(deg, part, offsets, cursor, N, E);
    scatter_kernel<<<(E + 255) / 256, 256, 0, stream>>>(dst, cursor, csr, E);
    eprep_kernel<<<(E + 255) / 256, 256, 0, stream>>>(csr, src, bond_type, bond_dir, esrc, ecomb, E);

    int mlp_grid = (N + 63) / 64;
    for (int l = 0; l < NLAYERS; ++l) {
        const uint* hin = (l & 1) ? h1 : h0;
        uint* hout      = (l & 1) ? h0 : h1;
        if (l < NLAYERS - 1)
            fused_mlp_kernel<true><<<mlp_grid, 512, 0, stream>>>(
                hin, etab + (size_t)l * 18 * D2, esrc, ecomb, offsets,
                (const uint4*)(w1h + (size_t)l * P1),
                (const uint4*)(w2h + (size_t)l * P2),
                b1 + (size_t)l * HD,
                scale2 + (size_t)l * D, shift2 + (size_t)l * D,
                hout, N);
        else
            fused_mlp_kernel<false><<<mlp_grid, 512, 0, stream>>>(
                hin, etab + (size_t)l * 18 * D2, esrc, ecomb, offsets,
                (const uint4*)(w1h + (size_t)l * P1),
                (const uint4*)(w2h + (size_t)l * P2),
                b1 + (size_t)l * HD,
                scale2 + (size_t)l * D, shift2 + (size_t)l * D,
                hout, N);
    }

    // final h is h1 (odd number of layers -> last write went to h1)
    pool_kernel<<<G, 320, 0, stream>>>((const ushort*)h1, graph_ids, gavg, N);
    head_kernel<<<G, 256, 0, stream>>>(gavg, Wd, bd, out);
}